// Round 3
// baseline (231.460 us; speedup 1.0000x reference)
//
#include <hip/hip_runtime.h>
#include <stdint.h>

typedef uint16_t u16;
typedef __attribute__((ext_vector_type(8))) short bf16x8;    // 8 bf16 (4 VGPRs)
typedef __attribute__((ext_vector_type(4))) float f32x4;     // MFMA C/D 16x16
typedef __attribute__((ext_vector_type(16))) float f32x16;   // MFMA C/D 32x32

#define EMB 768
#define NH 12
#define DK 64
#define BB 2
#define SS 2048
#define SCL 0.1803368801111244f   // 0.125 * log2(e)  (folded into Wq at pack time)
#define M0  24.0f                 // fixed softmax offset (log2 domain)

// counted waits + ordering fences for the ring-buffer GEMM cores
#define WAITV(n)  asm volatile("s_waitcnt vmcnt(" #n ")" ::: "memory")
#define WAITVL(n) asm volatile("s_waitcnt vmcnt(" #n ") lgkmcnt(0)" ::: "memory")
#define FENCE()   asm volatile("" ::: "memory")

// round-to-nearest-even f32 -> bf16 (scalar, cold paths)
__device__ __forceinline__ u16 f2bf(float x) {
  union { float f; uint32_t u; } v; v.f = x;
  uint32_t r = v.u + 0x7fffu + ((v.u >> 16) & 1u);
  return (u16)(r >> 16);
}

// gfx950 HW packed cvt: lo16 = bf16(a), hi16 = bf16(b), RNE
__device__ __forceinline__ uint32_t pk2(float a, float b) {
  uint32_t d;
  asm("v_cvt_pk_bf16_f32 %0, %1, %2" : "=v"(d) : "v"(a), "v"(b));
  return d;
}

__device__ __forceinline__ void gld16(const u16* g, u16* l) {
  __builtin_amdgcn_global_load_lds((const __attribute__((address_space(1))) void*)g,
                                   (__attribute__((address_space(3))) void*)l, 16, 0, 0);
}

// ---------------- fused pack kernel (weights + transposed mask words) ----------------
// Mask repack: u64 word W[b][qg][tg][r] (qg=q>>5, tg=t>>5, r=0..15), bit l (lane) =
//   mask[b][qg*32 + (l&31)][tg*32 + (r&3) + 8*(r>>2) + 4*(l>>5)] != 0
__global__ void pack_all(const float* __restrict__ wq, const float* __restrict__ wk,
                         const float* __restrict__ wv, const float* __restrict__ w,
                         const int* __restrict__ mask,
                         u16* __restrict__ wqkvT, u16* __restrict__ wT,
                         uint64_t* __restrict__ bits) {
  uint32_t tl = blockIdx.x * 256 + threadIdx.x;
  const uint32_t WTOT = 4u * EMB * EMB;     // 2359296, multiple of 256
  if (tl < WTOT) {
    int z = tl / (EMB * EMB);
    int t = tl - z * (EMB * EMB);
    int n = t / EMB, e = t - n * EMB;
    if (z < 3) {
      const float* src = z == 0 ? wq : (z == 1 ? wk : wv);
      float vv = src[((n >> 6) * EMB + e) * DK + (n & 63)];
      if (z == 0) vv *= SCL;                // fold score scale into Wq
      wqkvT[(size_t)z * EMB * EMB + t] = f2bf(vv);
    } else {
      wT[t] = f2bf(w[e * EMB + n]);
    }
  } else {
    uint32_t widx = tl - WTOT;              // [0, 524288): 8192 waves
    uint32_t wv64 = widx >> 6;
    uint32_t lane = widx & 63;
    uint32_t b  = wv64 >> 12;
    uint32_t qg = (wv64 >> 6) & 63;
    uint32_t tg = wv64 & 63;
    uint32_t c = lane & 31, hi = lane >> 5;
    const int* mp = mask + (((size_t)b * 2048 + qg * 32 + c) * 2048 + tg * 32 + hi * 4);
    int4 q0 = *(const int4*)mp;
    int4 q1 = *(const int4*)(mp + 8);
    int4 q2 = *(const int4*)(mp + 16);
    int4 q3 = *(const int4*)(mp + 24);
    uint64_t* wout = bits + (size_t)wv64 * 16;
    unsigned long long ball;
#define BAL(u, arr)                                                   \
    ball = __ballot(arr.x != 0); if (lane == 0) wout[u * 4 + 0] = ball; \
    ball = __ballot(arr.y != 0); if (lane == 0) wout[u * 4 + 1] = ball; \
    ball = __ballot(arr.z != 0); if (lane == 0) wout[u * 4 + 2] = ball; \
    ball = __ballot(arr.w != 0); if (lane == 0) wout[u * 4 + 3] = ball;
    BAL(0, q0) BAL(1, q1) BAL(2, q2) BAL(3, q3)
#undef BAL
  }
}

// ---------------- ring-4 counted-vmcnt GEMM cores (C = A * Bt^T), 64x128 tile ----------------
// 4 waves as 2x2: wave tile 32 rows x 64 cols, acc[2][4]. 8 MFMA / K-step. K=768 -> 24 steps.
// Ring of 4 LDS buffers, loads issued 2 steps ahead, raw s_barrier + counted vmcnt so
// next-tile loads stay in flight ACROSS the barrier (T3/T4 minimum form).
#define GEMM_MFMA_BODY64(Ab, Bb)                                                \
    bf16x8 af[2], bfr[4];                                                       \
    _Pragma("unroll")                                                           \
    for (int i = 0; i < 2; ++i)                                                 \
      af[i] = *(const bf16x8*)((Ab) + (wr * 32 + i * 16 + c) * 32 + quad * 8);  \
    _Pragma("unroll")                                                           \
    for (int j = 0; j < 4; ++j)                                                 \
      bfr[j] = *(const bf16x8*)((Bb) + (wc * 64 + j * 16 + c) * 32 + quad * 8); \
    _Pragma("unroll")                                                           \
    for (int i = 0; i < 2; ++i)                                                 \
      _Pragma("unroll")                                                         \
      for (int j = 0; j < 4; ++j)                                               \
        acc[i][j] = __builtin_amdgcn_mfma_f32_16x16x32_bf16(af[i], bfr[j], acc[i][j], 0, 0, 0);

// A f32 in global (reg-staged, HW-pk cvt to bf16); Bt packed bf16 via gld16 DMA.
__device__ __forceinline__ void gemm_f32A_ring(const float* __restrict__ A,
                                               const u16* __restrict__ Bt,
                                               int m0, int n0, u16* As, u16* Bs,
                                               f32x4 (&acc)[2][4]) {
  const int tid = threadIdx.x;
  const int lane = tid & 63, quad = lane >> 4, c = lane & 15;
  const int wr = (tid >> 6) >> 1, wc = (tid >> 6) & 1;
  const int arow = tid >> 2, acol = (tid & 3) * 8;   // 64 rows x 32 cols f32, 8/thread
  float4 a0, a1;
#define LOAD_A(kk)                                                     \
  {                                                                    \
    const float* src = A + (size_t)(m0 + arow) * EMB + (kk) + acol;    \
    a0 = *(const float4*)src; a1 = *(const float4*)(src + 4);          \
  }
#define WRITE_A(r4)                                                    \
  {                                                                    \
    uint4 pkv = { pk2(a0.x, a0.y), pk2(a0.z, a0.w),                    \
                  pk2(a1.x, a1.y), pk2(a1.z, a1.w) };                  \
    *(uint4*)(As + (r4) * 2048 + arow * 32 + acol) = pkv;              \
  }
#define ISSUE_B(kk, r4)                                                \
  _Pragma("unroll")                                                    \
  for (int r = 0; r < 2; ++r) {                                        \
    int bo = r * 4096 + tid * 16;                                      \
    gld16(Bt + (size_t)(n0 + (bo >> 6)) * EMB + (kk) + ((bo & 63) >> 1), \
          Bs + (r4) * 4096 + (bo >> 1));                               \
  }
  // prologue: tiles 0 and 1 in flight; A(0) staged to LDS
  LOAD_A(0); ISSUE_B(0, 0);
  WRITE_A(0);
  LOAD_A(32); ISSUE_B(32, 1);
#pragma unroll 4
  for (int t = 0; t < 24; ++t) {
    if (t + 1 < 24) WRITE_A((t + 1) & 3);      // regs hold A(t+1), loaded at t-1
    if (t + 1 < 24) { WAITVL(2); } else { WAITVL(0); }  // tile t landed; t+1 stays in flight
    __builtin_amdgcn_s_barrier();
    FENCE();
    if (t + 2 < 24) { LOAD_A(t * 32 + 64); ISSUE_B(t * 32 + 64, (t + 2) & 3); }
    const u16* Ab = As + (t & 3) * 2048;
    const u16* Bb = Bs + (t & 3) * 4096;
    GEMM_MFMA_BODY64(Ab, Bb)
  }
#undef LOAD_A
#undef WRITE_A
#undef ISSUE_B
}

// Both operands bf16 via gld16 DMA (3 DMA/thread/step).
__device__ __forceinline__ void gemm_bf16A_ring(const u16* __restrict__ A,
                                                const u16* __restrict__ Bt,
                                                int m0, int n0, u16* As, u16* Bs,
                                                f32x4 (&acc)[2][4]) {
  const int tid = threadIdx.x;
  const int lane = tid & 63, quad = lane >> 4, c = lane & 15;
  const int wr = (tid >> 6) >> 1, wc = (tid >> 6) & 1;
#define ISSUE_AB(kk, r4)                                               \
  {                                                                    \
    gld16(A + (size_t)(m0 + (tid >> 2)) * EMB + (kk) + (tid & 3) * 8,  \
          As + (r4) * 2048 + tid * 8);                                 \
    _Pragma("unroll")                                                  \
    for (int r = 0; r < 2; ++r) {                                      \
      int bo = r * 4096 + tid * 16;                                    \
      gld16(Bt + (size_t)(n0 + (bo >> 6)) * EMB + (kk) + ((bo & 63) >> 1), \
            Bs + (r4) * 4096 + (bo >> 1));                             \
    }                                                                  \
  }
  ISSUE_AB(0, 0);
  ISSUE_AB(32, 1);
#pragma unroll 4
  for (int t = 0; t < 24; ++t) {
    if (t + 1 < 24) { WAITV(3); } else { WAITV(0); }   // tile t landed; t+1 in flight
    __builtin_amdgcn_s_barrier();
    FENCE();
    if (t + 2 < 24) { ISSUE_AB(t * 32 + 64, (t + 2) & 3); }
    const u16* Ab = As + (t & 3) * 2048;
    const u16* Bb = Bs + (t & 3) * 4096;
    GEMM_MFMA_BODY64(Ab, Bb)
  }
#undef ISSUE_AB
}

// z=0: Q -> Qp[b,s,h*64+d]; z=1: K -> Kp same; z=2: V -> Vt[bh][d][t]
// 1-D grid 1152, XCD-panel swizzle: each XCD owns 24 A-panels x 6 n-tiles.
__launch_bounds__(256, 3)
__global__ void gemm_qkv(const float* __restrict__ q, const float* __restrict__ k,
                         const float* __restrict__ v, const u16* __restrict__ wt3,
                         u16* __restrict__ Qp, u16* __restrict__ Kp, u16* __restrict__ Vt) {
  __shared__ __align__(16) u16 As[4 * 64 * 32];    // 16 KB ring
  __shared__ __align__(16) u16 Bs[4 * 128 * 32];   // 32 KB ring
  const int id = blockIdx.x;                 // 0..1151
  const int xcd = id & 7, s = id >> 3;       // s: 0..143
  const int panel = xcd * 24 + s / 6;        // 0..191 (z*64 + mtile)
  const int ntile = s - (s / 6) * 6;
  const int z = panel >> 6, mt = panel & 63;
  const int m0 = mt * 64, n0 = ntile * 128;
  const float* A = z == 0 ? q : (z == 1 ? k : v);
  const u16* Bt = wt3 + (size_t)z * EMB * EMB;
  f32x4 acc[2][4];
  const f32x4 fz = {0.f, 0.f, 0.f, 0.f};
#pragma unroll
  for (int i = 0; i < 2; ++i)
#pragma unroll
    for (int j = 0; j < 4; ++j) acc[i][j] = fz;
  gemm_f32A_ring(A, Bt, m0, n0, As, Bs, acc);
  const int tid = threadIdx.x, lane = tid & 63, quad = lane >> 4, c = lane & 15;
  const int wr = (tid >> 6) >> 1, wc = (tid >> 6) & 1;
  if (z < 2) {
    u16* C = z == 0 ? Qp : Kp;
#pragma unroll
    for (int i = 0; i < 2; ++i)
#pragma unroll
      for (int j = 0; j < 4; ++j) {
        int row = m0 + wr * 32 + i * 16 + quad * 4;
        int col = n0 + wc * 64 + j * 16 + c;
#pragma unroll
        for (int r = 0; r < 4; r += 2) {
          uint32_t d = pk2(acc[i][j][r], acc[i][j][r + 1]);
          C[(size_t)(row + r) * EMB + col] = (u16)d;
          C[(size_t)(row + r + 1) * EMB + col] = (u16)(d >> 16);
        }
      }
  } else {
#pragma unroll
    for (int i = 0; i < 2; ++i)
#pragma unroll
      for (int j = 0; j < 4; ++j) {
        int row = m0 + wr * 32 + i * 16 + quad * 4;   // + r -> consecutive s
        int col = n0 + wc * 64 + j * 16 + c;          // n = h*64+d
        int b = row >> 11, ss = row & 2047;
        int h = col >> 6, d = col & 63;
        uint2 pk = { pk2(acc[i][j][0], acc[i][j][1]), pk2(acc[i][j][2], acc[i][j][3]) };
        *(uint2*)(Vt + ((size_t)(b * NH + h) * DK + d) * SS + ss) = pk;
      }
  }
}

// 1-D grid 384, XCD-panel swizzle: each XCD owns 8 A-panels x 6 n-tiles.
__launch_bounds__(256, 3)
__global__ void gemm_out(const u16* __restrict__ A, const u16* __restrict__ Bt,
                         float* __restrict__ C) {
  __shared__ __align__(16) u16 As[4 * 64 * 32];
  __shared__ __align__(16) u16 Bs[4 * 128 * 32];
  const int id = blockIdx.x;                 // 0..383
  const int xcd = id & 7, s = id >> 3;       // s: 0..47
  const int panel = xcd * 8 + s / 6;         // 0..63
  const int ntile = s - (s / 6) * 6;
  const int m0 = panel * 64, n0 = ntile * 128;
  f32x4 acc[2][4];
  const f32x4 fz = {0.f, 0.f, 0.f, 0.f};
#pragma unroll
  for (int i = 0; i < 2; ++i)
#pragma unroll
    for (int j = 0; j < 4; ++j) acc[i][j] = fz;
  gemm_bf16A_ring(A, Bt, m0, n0, As, Bs, acc);
  const int tid = threadIdx.x, lane = tid & 63, quad = lane >> 4, c = lane & 15;
  const int wr = (tid >> 6) >> 1, wc = (tid >> 6) & 1;
#pragma unroll
  for (int i = 0; i < 2; ++i)
#pragma unroll
    for (int j = 0; j < 4; ++j)
#pragma unroll
      for (int r = 0; r < 4; ++r) {
        int row = m0 + wr * 32 + i * 16 + quad * 4 + r;
        int col = n0 + wc * 64 + j * 16 + c;
        C[(size_t)row * EMB + col] = acc[i][j][r];   // raw fp32
      }
}

// ---------------- flash attention v6: 32x32 swapped MFMA, in-register softmax ----------------
// Grid 768 (1D, XCD-swizzled): block = (bh, 64-q tile). 8 waves = (wq2: q 32-group) x (th: t slice).
__launch_bounds__(512, 4)
__global__ void attn(const u16* __restrict__ Qp, const u16* __restrict__ Kp,
                     const u16* __restrict__ Vt, const uint64_t* __restrict__ MW,
                     u16* __restrict__ AO) {
  // Ks: [2][128 t][72]  (18432 u16)   Vs: [2][64 d][136] (17408 u16)  = 71680 B
  __shared__ __align__(16) u16 sm[2 * 128 * 72 + 2 * 64 * 136];
  u16* Ks0 = sm;
  u16* Vs0 = sm + 2 * 128 * 72;

  const int tid = threadIdx.x, lane = tid & 63;
  const int c = lane & 31, hi = lane >> 5;
  const int w = tid >> 6;
  const int wq2 = w >> 2, th = w & 3;

  // XCD swizzle: blockIdx.x % 8 = XCD -> all 32 q-tiles of a head stay on one XCD (K/V L2-resident)
  const int wid = blockIdx.x;
  const int xcd = wid & 7, slot = wid >> 3;        // slot 0..95
  const int bh = xcd + 8 * (slot >> 5);            // 0..23
  const int mtile = slot & 31;
  const int b = bh / NH, h = bh - b * NH;
  const int m0 = mtile * 64;

  const size_t qkbase = (size_t)b * SS * EMB + (size_t)h * DK;
  const size_t vtbase = (size_t)bh * DK * SS;

  // Q fragments (B-operand): lane holds Q[q = m0+wq2*32+c][k = ks*16 + hi*8 + e]
  bf16x8 aq[4];
  {
    const u16* qr = Qp + qkbase + (size_t)(m0 + wq2 * 32 + c) * EMB + hi * 8;
    aq[0] = *(const bf16x8*)(qr);
    aq[1] = *(const bf16x8*)(qr + 16);
    aq[2] = *(const bf16x8*)(qr + 32);
    aq[3] = *(const bf16x8*)(qr + 48);
  }

  // staging: K tile 128x64, V^T tile 64x128 -> 32B per thread each array
  const int srK = tid >> 2, scK = (tid & 3) * 16;
  const int srV = tid >> 3, scV = (tid & 7) * 16;
  const u16* gK = Kp + qkbase + (size_t)srK * EMB + scK;
  const u16* gV = Vt + vtbase + (size_t)srV * SS + scV;
  bf16x8 kr0, kr1, vr0, vr1;
#define LOADKV(t0) {                                             \
    const u16* gk_ = gK + (size_t)(t0) * EMB;                    \
    kr0 = *(const bf16x8*)gk_; kr1 = *(const bf16x8*)(gk_ + 8);  \
    const u16* gv_ = gV + (t0);                                  \
    vr0 = *(const bf16x8*)gv_; vr1 = *(const bf16x8*)(gv_ + 8); }
#define STOREKV(buf) {                                           \
    u16* ks_ = Ks0 + (buf) * (128 * 72) + srK * 72 + scK;        \
    *(bf16x8*)ks_ = kr0; *(bf16x8*)(ks_ + 8) = kr1;              \
    u16* vs_ = Vs0 + (buf) * (64 * 136) + srV * 136 + scV;       \
    *(bf16x8*)vs_ = vr0; *(bf16x8*)(vs_ + 8) = vr1; }

  // wave-uniform mask word base (scalar loads)
  const int thu = __builtin_amdgcn_readfirstlane(th);
  const int qgu = __builtin_amdgcn_readfirstlane(mtile * 2 + wq2);
  const uint64_t* mwb = MW + (((size_t)b * 64 + qgu) * 64) * 16 + thu * 16;
#define LOADMSK(m, it) {                                         \
    const uint64_t* mp_ = mwb + (size_t)(it) * 64;               \
    _Pragma("unroll")                                            \
    for (int r_ = 0; r_ < 16; ++r_) m[r_] = mp_[r_]; }

  float fNEG = -1e9f, fM0 = -M0;
  float lr = 0.f;
  f32x16 o0, o1;
#pragma unroll
  for (int r_ = 0; r_ < 16; ++r_) { o0[r_] = 0.f; o1[r_] = 0.f; }

  uint64_t mA[16], mB[16];
  LOADKV(0); LOADMSK(mA, 0);

#define BODY(it, buf, mc, mn) {                                                   \
    STOREKV(buf);                                                                 \
    __syncthreads();                                                              \
    if ((it) < 15) { LOADKV(((it) + 1) * 128); LOADMSK(mn, (it) + 1); }           \
    /* C-init: s[r] = maskbit ? -M0 : -1e9  (one cndmask/elem, SGPR-pair mask) */ \
    f32x16 s;                                                                     \
    _Pragma("unroll")                                                             \
    for (int r_ = 0; r_ < 16; ++r_) {                                             \
      float t_;                                                                   \
      asm("v_cndmask_b32 %0, %1, %2, %3"                                          \
          : "=v"(t_) : "v"(fNEG), "v"(fM0), "s"(mc[r_]));                         \
      s[r_] = t_;                                                                 \
    }                                                                             \
    /* S^T = K * Q^T over k=64 (4 chunks) */                                      \
    const u16* kb_ = Ks0 + (buf) * (128 * 72) + (th * 32 + c) * 72 + hi * 8;      \
    _Pragma("unroll")                                                             \
    for (int ks_ = 0; ks_ < 4; ++ks_) {                                           \
      bf16x8 kf_ = *(const bf16x8*)(kb_ + ks_ * 16);                              \
      s = __builtin_amdgcn_mfma_f32_32x32x16_bf16(kf_, aq[ks_], s, 0, 0, 0);      \
    }                                                                             \
    /* p = exp2(s); masked entries -> exp2(-1e9) = 0 */                           \
    _Pragma("unroll")                                                             \
    for (int r_ = 0; r_ < 16; ++r_) s[r_] = __builtin_amdgcn_exp2f(s[r_]);        \
    lr += ((s[0] + s[1]) + (s[2] + s[3])) + ((s[4] + s[5]) + (s[6] + s[7]))       \
        + ((s[8] + s[9]) + (s[10] + s[11])) + ((s[12] + s[13]) + (s[14] + s[15]));\
    /* in-register P -> PV B-frags: 8 pk2 + 4 permlane32_swap */                  \
    uint32_t x0 = pk2(s[0], s[1]),  x1 = pk2(s[2], s[3]);                         \
    uint32_t y0 = pk2(s[4], s[5]),  y1 = pk2(s[6], s[7]);                         \
    uint32_t z0 = pk2(s[8], s[9]),  z1 = pk2(s[10], s[11]);                       \
    uint32_t w0 = pk2(s[12], s[13]), w1 = pk2(s[14], s[15]);                      \
    asm("v_permlane32_swap_b32 %0, %1" : "+v"(x0), "+v"(y0));                     \
    asm("v_permlane32_swap_b32 %0, %1" : "+v"(x1), "+v"(y1));                     \
    asm("v_permlane32_swap_b32 %0, %1" : "+v"(z0), "+v"(w0));                     \
    asm("v_permlane32_swap_b32 %0, %1" : "+v"(z1), "+v"(w1));                     \
    bf16x8 pa0, pa1;                                                              \
    { union { uint32_t u[4]; bf16x8 v; } cv;                                      \
      cv.u[0] = x0; cv.u[1] = x1; cv.u[2] = y0; cv.u[3] = y1; pa0 = cv.v;         \
      cv.u[0] = z0; cv.u[1] = z1; cv.u[2] = w0; cv.u[3] = w1; pa1 = cv.v; }       \
    /* O^T += V^T * P^T : 2 d-groups x 2 t-chunks */                              \
    const u16* vb_ = Vs0 + (buf) * (64 * 136) + c * 136 + th * 32 + hi * 8;       \
    {                                                                             \
      bf16x8 vf_;                                                                 \
      vf_ = *(const bf16x8*)(vb_);                                                \
      o0 = __builtin_amdgcn_mfma_f32_32x32x16_bf16(vf_, pa0, o0, 0, 0, 0);        \
      vf_ = *(const bf16x8*)(vb_ + 16);                                           \
      o0 = __builtin_amdgcn_mfma_f32_32x32x16_bf16(vf_, pa1, o0, 0, 0, 0);        \
      vf_ = *(const bf16x8*)(vb_ + 32 * 136);                                     \
      o1 = __builtin_amdgcn_mfma_f32_32x32x16_bf16(vf_, pa0, o1, 0, 0, 0);        \
      vf_ = *(const bf16x8*)(vb_ + 32 * 136 + 16);                                \
      o1 = __builtin_amdgcn_mfma_f32_32x32x16_bf16(vf_, pa1, o1, 0, 0, 0);        \
    } }

  for (int i2 = 0; i2 < 8; ++i2) {
    BODY(i2 * 2,     0, mA, mB)
    BODY(i2 * 2 + 1, 1, mB, mA)
  }
#undef BODY
#undef LOADKV
#undef STOREKV
#undef LOADMSK

  // ---- cross-th reduction: partial O^T (f32) + partial l through LDS ----
  lr += __shfl_xor(lr, 32);                 // combine hi halves -> per-row partial for this th
  __syncthreads();                          // all waves done with Ks/Vs
  float* Of = (float*)sm;                   // [4 th][64 row][65]   (66560 B)
  float* Lf = (float*)sm + 4 * 64 * 65;     // [64 row][4 th]       (+1024 B) = 67584 <= 71680
  {
    int row = wq2 * 32 + c;
#pragma unroll
    for (int r_ = 0; r_ < 16; ++r_) {
      int d = (r_ & 3) + 8 * (r_ >> 2) + 4 * hi;
      Of[(th * 64 + row) * 65 + d]      = o0[r_];
      Of[(th * 64 + row) * 65 + 32 + d] = o1[r_];
    }
    if (hi == 0) Lf[row * 4 + th] = lr;
  }
  __syncthreads();
  {
    int qrow = tid >> 3, d0 = (tid & 7) * 8;
    float lt = Lf[qrow * 4 + 0] + Lf[qrow * 4 + 1] + Lf[qrow * 4 + 2] + Lf[qrow * 4 + 3];
    float inv = 1.f / fmaxf(lt, 1e-20f);
    float acc[8];
#pragma unroll
    for (int e = 0; e < 8; ++e) acc[e] = 0.f;
#pragma unroll
    for (int t_ = 0; t_ < 4; ++t_)
#pragma unroll
      for (int e = 0; e < 8; ++e) acc[e] += Of[(t_ * 64 + qrow) * 65 + d0 + e];
    uint32_t dw[4];
#pragma unroll
    for (int e = 0; e < 4; ++e) dw[e] = pk2(acc[2 * e] * inv, acc[2 * e + 1] * inv);
    *(uint4*)(AO + qkbase + (size_t)(m0 + qrow) * EMB + d0) = *(uint4*)dw;
  }
}

extern "C" void kernel_launch(void* const* d_in, const int* in_sizes, int n_in,
                              void* d_out, int out_size, void* d_ws, size_t ws_size,
                              hipStream_t stream) {
  const float* q  = (const float*)d_in[0];
  const float* k  = (const float*)d_in[1];
  const float* v  = (const float*)d_in[2];
  const int* mask = (const int*)d_in[3];
  const float* Wq = (const float*)d_in[4];
  const float* Wk = (const float*)d_in[5];
  const float* Wv = (const float*)d_in[6];
  const float* W  = (const float*)d_in[7];
  float* out = (float*)d_out;

  // d_out (12 MiB) as scratch for Kp + Vt, dead before gemm_out writes.
  u16* Kp = (u16*)d_out;                    // [b,s,h*64+d] bf16
  u16* Vt = (u16*)d_out + 3145728;          // [bh][d][t]   bf16

  // ws: 11.5 MiB
  u16* ws    = (u16*)d_ws;
  u16* Qp    = ws;                          // 3145728 u16; AO aliases
  u16* WqkvT = ws + 3145728;                // 1769472 u16
  u16* WT    = ws + 3145728 + 1769472;      // 589824 u16
  uint64_t* mb64 = (uint64_t*)(ws + 5505024); // 131072 u64 = 1 MiB
  u16* AO = Qp;

  pack_all<<<dim3(11264), 256, 0, stream>>>(Wq, Wk, Wv, W, mask, WqkvT, WT, mb64);
  gemm_qkv<<<dim3(1152), 256, 0, stream>>>(q, k, v, WqkvT, Qp, Kp, Vt);
  attn<<<dim3(768), 512, 0, stream>>>(Qp, Kp, Vt, mb64, AO);
  gemm_out<<<dim3(384), 256, 0, stream>>>(AO, WT, out);
}

// Round 7
// 226.588 us; speedup vs baseline: 1.0215x; 1.0215x over previous
//
#include <hip/hip_runtime.h>
#include <stdint.h>

typedef uint16_t u16;
typedef __attribute__((ext_vector_type(8))) short bf16x8;    // 8 bf16 (4 VGPRs)
typedef __attribute__((ext_vector_type(4))) float f32x4;     // MFMA C/D 16x16
typedef __attribute__((ext_vector_type(16))) float f32x16;   // MFMA C/D 32x32

#define EMB 768
#define NH 12
#define DK 64
#define BB 2
#define SS 2048
#define SCL 0.1803368801111244f   // 0.125 * log2(e)  (folded into Wq at pack time)
#define M0  24.0f                 // fixed softmax offset (log2 domain)

// round-to-nearest-even f32 -> bf16 (scalar, cold paths)
__device__ __forceinline__ u16 f2bf(float x) {
  union { float f; uint32_t u; } v; v.f = x;
  uint32_t r = v.u + 0x7fffu + ((v.u >> 16) & 1u);
  return (u16)(r >> 16);
}

// gfx950 HW packed cvt: lo16 = bf16(a), hi16 = bf16(b), RNE
__device__ __forceinline__ uint32_t pk2(float a, float b) {
  uint32_t d;
  asm("v_cvt_pk_bf16_f32 %0, %1, %2" : "=v"(d) : "v"(a), "v"(b));
  return d;
}

__device__ __forceinline__ void gld16(const u16* g, u16* l) {
  __builtin_amdgcn_global_load_lds((const __attribute__((address_space(1))) void*)g,
                                   (__attribute__((address_space(3))) void*)l, 16, 0, 0);
}

// ---------------- fused pack kernel (weights + transposed mask words) ----------------
// Mask repack: u64 word W[b][qg][tg][r] (qg=q>>5, tg=t>>5, r=0..15), bit l (lane) =
//   mask[b][qg*32 + (l&31)][tg*32 + (r&3) + 8*(r>>2) + 4*(l>>5)] != 0
__global__ void pack_all(const float* __restrict__ wq, const float* __restrict__ wk,
                         const float* __restrict__ wv, const float* __restrict__ w,
                         const int* __restrict__ mask,
                         u16* __restrict__ wqkvT, u16* __restrict__ wT,
                         uint64_t* __restrict__ bits) {
  uint32_t tl = blockIdx.x * 256 + threadIdx.x;
  const uint32_t WTOT = 4u * EMB * EMB;     // 2359296, multiple of 256
  if (tl < WTOT) {
    int z = tl / (EMB * EMB);
    int t = tl - z * (EMB * EMB);
    int n = t / EMB, e = t - n * EMB;
    if (z < 3) {
      const float* src = z == 0 ? wq : (z == 1 ? wk : wv);
      float vv = src[((n >> 6) * EMB + e) * DK + (n & 63)];
      if (z == 0) vv *= SCL;                // fold score scale into Wq
      wqkvT[(size_t)z * EMB * EMB + t] = f2bf(vv);
    } else {
      wT[t] = f2bf(w[e * EMB + n]);
    }
  } else {
    uint32_t widx = tl - WTOT;              // [0, 524288): 8192 waves
    uint32_t wv64 = widx >> 6;
    uint32_t lane = widx & 63;
    uint32_t b  = wv64 >> 12;
    uint32_t qg = (wv64 >> 6) & 63;
    uint32_t tg = wv64 & 63;
    uint32_t c = lane & 31, hi = lane >> 5;
    const int* mp = mask + (((size_t)b * 2048 + qg * 32 + c) * 2048 + tg * 32 + hi * 4);
    int4 q0 = *(const int4*)mp;
    int4 q1 = *(const int4*)(mp + 8);
    int4 q2 = *(const int4*)(mp + 16);
    int4 q3 = *(const int4*)(mp + 24);
    uint64_t* wout = bits + (size_t)wv64 * 16;
    unsigned long long ball;
#define BAL(u, arr)                                                   \
    ball = __ballot(arr.x != 0); if (lane == 0) wout[u * 4 + 0] = ball; \
    ball = __ballot(arr.y != 0); if (lane == 0) wout[u * 4 + 1] = ball; \
    ball = __ballot(arr.z != 0); if (lane == 0) wout[u * 4 + 2] = ball; \
    ball = __ballot(arr.w != 0); if (lane == 0) wout[u * 4 + 3] = ball;
    BAL(0, q0) BAL(1, q1) BAL(2, q2) BAL(3, q3)
#undef BAL
  }
}

// ---------------- pipelined GEMM cores (C = A * Bt^T), 64x128 tile, BK=64 ----------------
// R1's proven __syncthreads discipline (compiler-inserted waits), scaled to BK=64:
// 12 K-steps instead of 24 -> half the serial latency exposures, 16 MFMA/step.
__device__ __forceinline__ void gemm_f32A_pipe64(const float* __restrict__ A,
                                                 const u16* __restrict__ Bt,
                                                 int m0, int n0, u16* As, u16* Bs,
                                                 f32x4 (&acc)[2][4]) {
  const int tid = threadIdx.x;
  const int lane = tid & 63, quad = lane >> 4, c = lane & 15;
  const int wr = (tid >> 6) >> 1, wc = (tid >> 6) & 1;
  const int arow = tid >> 2, acol = (tid & 3) * 16;   // 64 rows x 64 f32 cols, 16/thread
  float4 a0, a1, a2, a3;
#define LOAD_A(kk)                                                     \
  {                                                                    \
    const float* src = A + (size_t)(m0 + arow) * EMB + (kk) + acol;    \
    a0 = *(const float4*)src;        a1 = *(const float4*)(src + 4);   \
    a2 = *(const float4*)(src + 8);  a3 = *(const float4*)(src + 12);  \
  }
#define ISSUE_B(kk, buf)                                               \
  _Pragma("unroll")                                                    \
  for (int r = 0; r < 4; ++r) {                                        \
    int bo = r * 4096 + tid * 16;  /* bytes in 128x64u16 (128B/row) */ \
    gld16(Bt + (size_t)(n0 + (bo >> 7)) * EMB + (kk) + ((bo & 127) >> 1), \
          Bs + (buf) * 8192 + (bo >> 1));                              \
  }
  LOAD_A(0); ISSUE_B(0, 0);
  for (int kk = 0; kk < EMB; kk += 64) {
    const int buf = (kk >> 6) & 1;
    {                                             // write A(kk) regs -> As[buf]
      uint4 p0 = { pk2(a0.x, a0.y), pk2(a0.z, a0.w), pk2(a1.x, a1.y), pk2(a1.z, a1.w) };
      uint4 p1 = { pk2(a2.x, a2.y), pk2(a2.z, a2.w), pk2(a3.x, a3.y), pk2(a3.z, a3.w) };
      *(uint4*)(As + buf * 4096 + arow * 64 + acol) = p0;
      *(uint4*)(As + buf * 4096 + arow * 64 + acol + 8) = p1;
    }
    __syncthreads();                              // drains B(kk) DMA + A writes
    if (kk + 64 < EMB) { LOAD_A(kk + 64); ISSUE_B(kk + 64, buf ^ 1); }
    const u16* Ab = As + buf * 4096;
    const u16* Bb = Bs + buf * 8192;
#pragma unroll
    for (int ks = 0; ks < 2; ++ks) {
      bf16x8 af_[2], bf_[4];
#pragma unroll
      for (int i = 0; i < 2; ++i)
        af_[i] = *(const bf16x8*)(Ab + (wr * 32 + i * 16 + c) * 64 + ks * 32 + quad * 8);
#pragma unroll
      for (int j = 0; j < 4; ++j)
        bf_[j] = *(const bf16x8*)(Bb + (wc * 64 + j * 16 + c) * 64 + ks * 32 + quad * 8);
#pragma unroll
      for (int i = 0; i < 2; ++i)
#pragma unroll
        for (int j = 0; j < 4; ++j)
          acc[i][j] = __builtin_amdgcn_mfma_f32_16x16x32_bf16(af_[i], bf_[j], acc[i][j], 0, 0, 0);
    }
  }
#undef LOAD_A
#undef ISSUE_B
}

__device__ __forceinline__ void gemm_bf16A_pipe64(const u16* __restrict__ A,
                                                  const u16* __restrict__ Bt,
                                                  int m0, int n0, u16* As, u16* Bs,
                                                  f32x4 (&acc)[2][4]) {
  const int tid = threadIdx.x;
  const int lane = tid & 63, quad = lane >> 4, c = lane & 15;
  const int wr = (tid >> 6) >> 1, wc = (tid >> 6) & 1;
#define ISSUE_AB(kk, buf)                                              \
  {                                                                    \
    _Pragma("unroll")                                                  \
    for (int r = 0; r < 2; ++r) {   /* A: 64x64 u16, 8KB/buf */        \
      int ao = r * 4096 + tid * 16;                                    \
      gld16(A + (size_t)(m0 + (ao >> 7)) * EMB + (kk) + ((ao & 127) >> 1), \
            As + (buf) * 4096 + (ao >> 1));                            \
    }                                                                  \
    _Pragma("unroll")                                                  \
    for (int r = 0; r < 4; ++r) {   /* B: 128x64 u16, 16KB/buf */      \
      int bo = r * 4096 + tid * 16;                                    \
      gld16(Bt + (size_t)(n0 + (bo >> 7)) * EMB + (kk) + ((bo & 127) >> 1), \
            Bs + (buf) * 8192 + (bo >> 1));                            \
    }                                                                  \
  }
  ISSUE_AB(0, 0);
  for (int kk = 0; kk < EMB; kk += 64) {
    const int buf = (kk >> 6) & 1;
    __syncthreads();                              // drains DMA(kk)
    if (kk + 64 < EMB) { ISSUE_AB(kk + 64, buf ^ 1); }
    const u16* Ab = As + buf * 4096;
    const u16* Bb = Bs + buf * 8192;
#pragma unroll
    for (int ks = 0; ks < 2; ++ks) {
      bf16x8 af_[2], bf_[4];
#pragma unroll
      for (int i = 0; i < 2; ++i)
        af_[i] = *(const bf16x8*)(Ab + (wr * 32 + i * 16 + c) * 64 + ks * 32 + quad * 8);
#pragma unroll
      for (int j = 0; j < 4; ++j)
        bf_[j] = *(const bf16x8*)(Bb + (wc * 64 + j * 16 + c) * 64 + ks * 32 + quad * 8);
#pragma unroll
      for (int i = 0; i < 2; ++i)
#pragma unroll
        for (int j = 0; j < 4; ++j)
          acc[i][j] = __builtin_amdgcn_mfma_f32_16x16x32_bf16(af_[i], bf_[j], acc[i][j], 0, 0, 0);
    }
  }
#undef ISSUE_AB
}

// z=0: Q -> Qp[b,s,h*64+d]; z=1: K -> Kp same; z=2: V -> Vt[bh][d][t]
// 1-D grid 1152, XCD-panel swizzle: each XCD owns 24 A-panels x 6 n-tiles.
__launch_bounds__(256, 3)
__global__ void gemm_qkv(const float* __restrict__ q, const float* __restrict__ k,
                         const float* __restrict__ v, const u16* __restrict__ wt3,
                         u16* __restrict__ Qp, u16* __restrict__ Kp, u16* __restrict__ Vt) {
  __shared__ __align__(16) u16 As[2 * 64 * 64];    // 16 KB dbuf
  __shared__ __align__(16) u16 Bs[2 * 128 * 64];   // 32 KB dbuf
  const int id = blockIdx.x;                 // 0..1151
  const int xcd = id & 7, s = id >> 3;       // s: 0..143
  const int panel = xcd * 24 + s / 6;        // 0..191 (z*64 + mtile)
  const int ntile = s - (s / 6) * 6;
  const int z = panel >> 6, mt = panel & 63;
  const int m0 = mt * 64, n0 = ntile * 128;
  const float* A = z == 0 ? q : (z == 1 ? k : v);
  const u16* Bt = wt3 + (size_t)z * EMB * EMB;
  f32x4 acc[2][4];
  const f32x4 fz = {0.f, 0.f, 0.f, 0.f};
#pragma unroll
  for (int i = 0; i < 2; ++i)
#pragma unroll
    for (int j = 0; j < 4; ++j) acc[i][j] = fz;
  gemm_f32A_pipe64(A, Bt, m0, n0, As, Bs, acc);
  const int tid = threadIdx.x, lane = tid & 63, quad = lane >> 4, c = lane & 15;
  const int wr = (tid >> 6) >> 1, wc = (tid >> 6) & 1;
  if (z < 2) {
    u16* C = z == 0 ? Qp : Kp;
#pragma unroll
    for (int i = 0; i < 2; ++i)
#pragma unroll
      for (int j = 0; j < 4; ++j) {
        int row = m0 + wr * 32 + i * 16 + quad * 4;
        int col = n0 + wc * 64 + j * 16 + c;
#pragma unroll
        for (int r = 0; r < 4; r += 2) {
          uint32_t d = pk2(acc[i][j][r], acc[i][j][r + 1]);
          C[(size_t)(row + r) * EMB + col] = (u16)d;
          C[(size_t)(row + r + 1) * EMB + col] = (u16)(d >> 16);
        }
      }
  } else {
#pragma unroll
    for (int i = 0; i < 2; ++i)
#pragma unroll
      for (int j = 0; j < 4; ++j) {
        int row = m0 + wr * 32 + i * 16 + quad * 4;   // + r -> consecutive s
        int col = n0 + wc * 64 + j * 16 + c;          // n = h*64+d
        int b = row >> 11, ss = row & 2047;
        int h = col >> 6, d = col & 63;
        uint2 pk = { pk2(acc[i][j][0], acc[i][j][1]), pk2(acc[i][j][2], acc[i][j][3]) };
        *(uint2*)(Vt + ((size_t)(b * NH + h) * DK + d) * SS + ss) = pk;
      }
  }
}

// 1-D grid 384, XCD-panel swizzle: each XCD owns 8 A-panels x 6 n-tiles.
__launch_bounds__(256, 3)
__global__ void gemm_out(const u16* __restrict__ A, const u16* __restrict__ Bt,
                         float* __restrict__ C) {
  __shared__ __align__(16) u16 As[2 * 64 * 64];    // 16 KB dbuf
  __shared__ __align__(16) u16 Bs[2 * 128 * 64];   // 32 KB dbuf
  const int id = blockIdx.x;                 // 0..383
  const int xcd = id & 7, s = id >> 3;       // s: 0..47
  const int panel = xcd * 8 + s / 6;         // 0..63
  const int ntile = s - (s / 6) * 6;
  const int m0 = panel * 64, n0 = ntile * 128;
  f32x4 acc[2][4];
  const f32x4 fz = {0.f, 0.f, 0.f, 0.f};
#pragma unroll
  for (int i = 0; i < 2; ++i)
#pragma unroll
    for (int j = 0; j < 4; ++j) acc[i][j] = fz;
  gemm_bf16A_pipe64(A, Bt, m0, n0, As, Bs, acc);
  const int tid = threadIdx.x, lane = tid & 63, quad = lane >> 4, c = lane & 15;
  const int wr = (tid >> 6) >> 1, wc = (tid >> 6) & 1;
#pragma unroll
  for (int i = 0; i < 2; ++i)
#pragma unroll
    for (int j = 0; j < 4; ++j)
#pragma unroll
      for (int r = 0; r < 4; ++r) {
        int row = m0 + wr * 32 + i * 16 + quad * 4 + r;
        int col = n0 + wc * 64 + j * 16 + c;
        C[(size_t)row * EMB + col] = acc[i][j][r];   // raw fp32
      }
}

// ---------------- flash attention v6: 32x32 swapped MFMA, in-register softmax ----------------
// Grid 768 (1D, XCD-swizzled): block = (bh, 64-q tile). 8 waves = (wq2: q 32-group) x (th: t slice).
__launch_bounds__(512, 4)
__global__ void attn(const u16* __restrict__ Qp, const u16* __restrict__ Kp,
                     const u16* __restrict__ Vt, const uint64_t* __restrict__ MW,
                     u16* __restrict__ AO) {
  // Ks: [2][128 t][72]  (18432 u16)   Vs: [2][64 d][136] (17408 u16)  = 71680 B
  __shared__ __align__(16) u16 sm[2 * 128 * 72 + 2 * 64 * 136];
  u16* Ks0 = sm;
  u16* Vs0 = sm + 2 * 128 * 72;

  const int tid = threadIdx.x, lane = tid & 63;
  const int c = lane & 31, hi = lane >> 5;
  const int w = tid >> 6;
  const int wq2 = w >> 2, th = w & 3;

  // XCD swizzle: blockIdx.x % 8 = XCD -> all 32 q-tiles of a head stay on one XCD (K/V L2-resident)
  const int wid = blockIdx.x;
  const int xcd = wid & 7, slot = wid >> 3;        // slot 0..95
  const int bh = xcd + 8 * (slot >> 5);            // 0..23
  const int mtile = slot & 31;
  const int b = bh / NH, h = bh - b * NH;
  const int m0 = mtile * 64;

  const size_t qkbase = (size_t)b * SS * EMB + (size_t)h * DK;
  const size_t vtbase = (size_t)bh * DK * SS;

  // Q fragments (B-operand): lane holds Q[q = m0+wq2*32+c][k = ks*16 + hi*8 + e]
  bf16x8 aq[4];
  {
    const u16* qr = Qp + qkbase + (size_t)(m0 + wq2 * 32 + c) * EMB + hi * 8;
    aq[0] = *(const bf16x8*)(qr);
    aq[1] = *(const bf16x8*)(qr + 16);
    aq[2] = *(const bf16x8*)(qr + 32);
    aq[3] = *(const bf16x8*)(qr + 48);
  }

  // staging: K tile 128x64, V^T tile 64x128 -> 32B per thread each array
  const int srK = tid >> 2, scK = (tid & 3) * 16;
  const int srV = tid >> 3, scV = (tid & 7) * 16;
  const u16* gK = Kp + qkbase + (size_t)srK * EMB + scK;
  const u16* gV = Vt + vtbase + (size_t)srV * SS + scV;
  bf16x8 kr0, kr1, vr0, vr1;
#define LOADKV(t0) {                                             \
    const u16* gk_ = gK + (size_t)(t0) * EMB;                    \
    kr0 = *(const bf16x8*)gk_; kr1 = *(const bf16x8*)(gk_ + 8);  \
    const u16* gv_ = gV + (t0);                                  \
    vr0 = *(const bf16x8*)gv_; vr1 = *(const bf16x8*)(gv_ + 8); }
#define STOREKV(buf) {                                           \
    u16* ks_ = Ks0 + (buf) * (128 * 72) + srK * 72 + scK;        \
    *(bf16x8*)ks_ = kr0; *(bf16x8*)(ks_ + 8) = kr1;              \
    u16* vs_ = Vs0 + (buf) * (64 * 136) + srV * 136 + scV;       \
    *(bf16x8*)vs_ = vr0; *(bf16x8*)(vs_ + 8) = vr1; }

  // wave-uniform mask word base (scalar loads)
  const int thu = __builtin_amdgcn_readfirstlane(th);
  const int qgu = __builtin_amdgcn_readfirstlane(mtile * 2 + wq2);
  const uint64_t* mwb = MW + (((size_t)b * 64 + qgu) * 64) * 16 + thu * 16;
#define LOADMSK(m, it) {                                         \
    const uint64_t* mp_ = mwb + (size_t)(it) * 64;               \
    _Pragma("unroll")                                            \
    for (int r_ = 0; r_ < 16; ++r_) m[r_] = mp_[r_]; }

  float fNEG = -1e9f, fM0 = -M0;
  float lr = 0.f;
  f32x16 o0, o1;
#pragma unroll
  for (int r_ = 0; r_ < 16; ++r_) { o0[r_] = 0.f; o1[r_] = 0.f; }

  uint64_t mA[16], mB[16];
  LOADKV(0); LOADMSK(mA, 0);

#define BODY(it, buf, mc, mn) {                                                   \
    STOREKV(buf);                                                                 \
    __syncthreads();                                                              \
    if ((it) < 15) { LOADKV(((it) + 1) * 128); LOADMSK(mn, (it) + 1); }           \
    /* C-init: s[r] = maskbit ? -M0 : -1e9  (one cndmask/elem, SGPR-pair mask) */ \
    f32x16 s;                                                                     \
    _Pragma("unroll")                                                             \
    for (int r_ = 0; r_ < 16; ++r_) {                                             \
      float t_;                                                                   \
      asm("v_cndmask_b32 %0, %1, %2, %3"                                          \
          : "=v"(t_) : "v"(fNEG), "v"(fM0), "s"(mc[r_]));                         \
      s[r_] = t_;                                                                 \
    }                                                                             \
    /* S^T = K * Q^T over k=64 (4 chunks) */                                      \
    const u16* kb_ = Ks0 + (buf) * (128 * 72) + (th * 32 + c) * 72 + hi * 8;      \
    _Pragma("unroll")                                                             \
    for (int ks_ = 0; ks_ < 4; ++ks_) {                                           \
      bf16x8 kf_ = *(const bf16x8*)(kb_ + ks_ * 16);                              \
      s = __builtin_amdgcn_mfma_f32_32x32x16_bf16(kf_, aq[ks_], s, 0, 0, 0);      \
    }                                                                             \
    /* p = exp2(s); masked entries -> exp2(-1e9) = 0 */                           \
    _Pragma("unroll")                                                             \
    for (int r_ = 0; r_ < 16; ++r_) s[r_] = __builtin_amdgcn_exp2f(s[r_]);        \
    lr += ((s[0] + s[1]) + (s[2] + s[3])) + ((s[4] + s[5]) + (s[6] + s[7]))       \
        + ((s[8] + s[9]) + (s[10] + s[11])) + ((s[12] + s[13]) + (s[14] + s[15]));\
    /* in-register P -> PV B-frags: 8 pk2 + 4 permlane32_swap */                  \
    uint32_t x0 = pk2(s[0], s[1]),  x1 = pk2(s[2], s[3]);                         \
    uint32_t y0 = pk2(s[4], s[5]),  y1 = pk2(s[6], s[7]);                         \
    uint32_t z0 = pk2(s[8], s[9]),  z1 = pk2(s[10], s[11]);                       \
    uint32_t w0 = pk2(s[12], s[13]), w1 = pk2(s[14], s[15]);                      \
    asm("v_permlane32_swap_b32 %0, %1" : "+v"(x0), "+v"(y0));                     \
    asm("v_permlane32_swap_b32 %0, %1" : "+v"(x1), "+v"(y1));                     \
    asm("v_permlane32_swap_b32 %0, %1" : "+v"(z0), "+v"(w0));                     \
    asm("v_permlane32_swap_b32 %0, %1" : "+v"(z1), "+v"(w1));                     \
    bf16x8 pa0, pa1;                                                              \
    { union { uint32_t u[4]; bf16x8 v; } cv;                                      \
      cv.u[0] = x0; cv.u[1] = x1; cv.u[2] = y0; cv.u[3] = y1; pa0 = cv.v;         \
      cv.u[0] = z0; cv.u[1] = z1; cv.u[2] = w0; cv.u[3] = w1; pa1 = cv.v; }       \
    /* O^T += V^T * P^T : 2 d-groups x 2 t-chunks */                              \
    const u16* vb_ = Vs0 + (buf) * (64 * 136) + c * 136 + th * 32 + hi * 8;       \
    {                                                                             \
      bf16x8 vf_;                                                                 \
      vf_ = *(const bf16x8*)(vb_);                                                \
      o0 = __builtin_amdgcn_mfma_f32_32x32x16_bf16(vf_, pa0, o0, 0, 0, 0);        \
      vf_ = *(const bf16x8*)(vb_ + 16);                                           \
      o0 = __builtin_amdgcn_mfma_f32_32x32x16_bf16(vf_, pa1, o0, 0, 0, 0);        \
      vf_ = *(const bf16x8*)(vb_ + 32 * 136);                                     \
      o1 = __builtin_amdgcn_mfma_f32_32x32x16_bf16(vf_, pa0, o1, 0, 0, 0);        \
      vf_ = *(const bf16x8*)(vb_ + 32 * 136 + 16);                                \
      o1 = __builtin_amdgcn_mfma_f32_32x32x16_bf16(vf_, pa1, o1, 0, 0, 0);        \
    } }

  for (int i2 = 0; i2 < 8; ++i2) {
    BODY(i2 * 2,     0, mA, mB)
    BODY(i2 * 2 + 1, 1, mB, mA)
  }
#undef BODY
#undef LOADKV
#undef STOREKV
#undef LOADMSK

  // ---- cross-th reduction: partial O^T (f32) + partial l through LDS ----
  lr += __shfl_xor(lr, 32);                 // combine hi halves -> per-row partial for this th
  __syncthreads();                          // all waves done with Ks/Vs
  float* Of = (float*)sm;                   // [4 th][64 row][65]   (66560 B)
  float* Lf = (float*)sm + 4 * 64 * 65;     // [64 row][4 th]       (+1024 B) = 67584 <= 71680
  {
    int row = wq2 * 32 + c;
#pragma unroll
    for (int r_ = 0; r_ < 16; ++r_) {
      int d = (r_ & 3) + 8 * (r_ >> 2) + 4 * hi;
      Of[(th * 64 + row) * 65 + d]      = o0[r_];
      Of[(th * 64 + row) * 65 + 32 + d] = o1[r_];
    }
    if (hi == 0) Lf[row * 4 + th] = lr;
  }
  __syncthreads();
  {
    int qrow = tid >> 3, d0 = (tid & 7) * 8;
    float lt = Lf[qrow * 4 + 0] + Lf[qrow * 4 + 1] + Lf[qrow * 4 + 2] + Lf[qrow * 4 + 3];
    float inv = 1.f / fmaxf(lt, 1e-20f);
    float acc[8];
#pragma unroll
    for (int e = 0; e < 8; ++e) acc[e] = 0.f;
#pragma unroll
    for (int t_ = 0; t_ < 4; ++t_)
#pragma unroll
      for (int e = 0; e < 8; ++e) acc[e] += Of[(t_ * 64 + qrow) * 65 + d0 + e];
    uint32_t dw[4];
#pragma unroll
    for (int e = 0; e < 4; ++e) dw[e] = pk2(acc[2 * e] * inv, acc[2 * e + 1] * inv);
    *(uint4*)(AO + qkbase + (size_t)(m0 + qrow) * EMB + d0) = *(uint4*)dw;
  }
}

extern "C" void kernel_launch(void* const* d_in, const int* in_sizes, int n_in,
                              void* d_out, int out_size, void* d_ws, size_t ws_size,
                              hipStream_t stream) {
  const float* q  = (const float*)d_in[0];
  const float* k  = (const float*)d_in[1];
  const float* v  = (const float*)d_in[2];
  const int* mask = (const int*)d_in[3];
  const float* Wq = (const float*)d_in[4];
  const float* Wk = (const float*)d_in[5];
  const float* Wv = (const float*)d_in[6];
  const float* W  = (const float*)d_in[7];
  float* out = (float*)d_out;

  // d_out (12 MiB) as scratch for Kp + Vt, dead before gemm_out writes.
  u16* Kp = (u16*)d_out;                    // [b,s,h*64+d] bf16
  u16* Vt = (u16*)d_out + 3145728;          // [bh][d][t]   bf16

  // ws: 11.5 MiB
  u16* ws    = (u16*)d_ws;
  u16* Qp    = ws;                          // 3145728 u16; AO aliases
  u16* WqkvT = ws + 3145728;                // 1769472 u16
  u16* WT    = ws + 3145728 + 1769472;      // 589824 u16
  uint64_t* mb64 = (uint64_t*)(ws + 5505024); // 131072 u64 = 1 MiB
  u16* AO = Qp;

  pack_all<<<dim3(11264), 256, 0, stream>>>(Wq, Wk, Wv, W, mask, WqkvT, WT, mb64);
  gemm_qkv<<<dim3(1152), 256, 0, stream>>>(q, k, v, WqkvT, Qp, Kp, Vt);
  attn<<<dim3(768), 512, 0, stream>>>(Qp, Kp, Vt, mb64, AO);
  gemm_out<<<dim3(384), 256, 0, stream>>>(AO, WT, out);
}

// Round 8
// 224.556 us; speedup vs baseline: 1.0307x; 1.0091x over previous
//
#include <hip/hip_runtime.h>
#include <stdint.h>

typedef uint16_t u16;
typedef __attribute__((ext_vector_type(8))) short bf16x8;    // 8 bf16 (4 VGPRs)
typedef __attribute__((ext_vector_type(4))) float f32x4;     // MFMA C/D 16x16
typedef __attribute__((ext_vector_type(16))) float f32x16;   // MFMA C/D 32x32

#define EMB 768
#define NH 12
#define DK 64
#define BB 2
#define SS 2048
#define SCL 0.1803368801111244f   // 0.125 * log2(e)  (folded into Wq at pack time)
#define M0  24.0f                 // fixed softmax offset (log2 domain)

// round-to-nearest-even f32 -> bf16 (scalar, cold paths)
__device__ __forceinline__ u16 f2bf(float x) {
  union { float f; uint32_t u; } v; v.f = x;
  uint32_t r = v.u + 0x7fffu + ((v.u >> 16) & 1u);
  return (u16)(r >> 16);
}

// gfx950 HW packed cvt: lo16 = bf16(a), hi16 = bf16(b), RNE
__device__ __forceinline__ uint32_t pk2(float a, float b) {
  uint32_t d;
  asm("v_cvt_pk_bf16_f32 %0, %1, %2" : "=v"(d) : "v"(a), "v"(b));
  return d;
}

__device__ __forceinline__ void gld16(const u16* g, u16* l) {
  __builtin_amdgcn_global_load_lds((const __attribute__((address_space(1))) void*)g,
                                   (__attribute__((address_space(3))) void*)l, 16, 0, 0);
}

// ---------------- fused pack kernel (weights + transposed mask words) ----------------
// Mask repack: u64 word W[b][qg][tg][r] (qg=q>>5, tg=t>>5, r=0..15), bit l (lane) =
//   mask[b][qg*32 + (l&31)][tg*32 + (r&3) + 8*(r>>2) + 4*(l>>5)] != 0
__global__ void pack_all(const float* __restrict__ wq, const float* __restrict__ wk,
                         const float* __restrict__ wv, const float* __restrict__ w,
                         const int* __restrict__ mask,
                         u16* __restrict__ wqkvT, u16* __restrict__ wT,
                         uint64_t* __restrict__ bits) {
  uint32_t tl = blockIdx.x * 256 + threadIdx.x;
  const uint32_t WTOT = 4u * EMB * EMB;     // 2359296, multiple of 256
  if (tl < WTOT) {
    int z = tl / (EMB * EMB);
    int t = tl - z * (EMB * EMB);
    int n = t / EMB, e = t - n * EMB;
    if (z < 3) {
      const float* src = z == 0 ? wq : (z == 1 ? wk : wv);
      float vv = src[((n >> 6) * EMB + e) * DK + (n & 63)];
      if (z == 0) vv *= SCL;                // fold score scale into Wq
      wqkvT[(size_t)z * EMB * EMB + t] = f2bf(vv);
    } else {
      wT[t] = f2bf(w[e * EMB + n]);
    }
  } else {
    uint32_t widx = tl - WTOT;              // [0, 524288): 8192 waves
    uint32_t wv64 = widx >> 6;
    uint32_t lane = widx & 63;
    uint32_t b  = wv64 >> 12;
    uint32_t qg = (wv64 >> 6) & 63;
    uint32_t tg = wv64 & 63;
    uint32_t c = lane & 31, hi = lane >> 5;
    const int* mp = mask + (((size_t)b * 2048 + qg * 32 + c) * 2048 + tg * 32 + hi * 4);
    int4 q0 = *(const int4*)mp;
    int4 q1 = *(const int4*)(mp + 8);
    int4 q2 = *(const int4*)(mp + 16);
    int4 q3 = *(const int4*)(mp + 24);
    uint64_t* wout = bits + (size_t)wv64 * 16;
    unsigned long long ball;
#define BAL(u, arr)                                                   \
    ball = __ballot(arr.x != 0); if (lane == 0) wout[u * 4 + 0] = ball; \
    ball = __ballot(arr.y != 0); if (lane == 0) wout[u * 4 + 1] = ball; \
    ball = __ballot(arr.z != 0); if (lane == 0) wout[u * 4 + 2] = ball; \
    ball = __ballot(arr.w != 0); if (lane == 0) wout[u * 4 + 3] = ball;
    BAL(0, q0) BAL(1, q1) BAL(2, q2) BAL(3, q3)
#undef BAL
  }
}

// ---------------- pipelined GEMM cores (C = A * Bt^T), 64x128 tile, BK=32 ----------------
// R1's proven __syncthreads discipline + bank-conflict-free XOR swizzle (T2, m173/m201):
// LDS dest stays LINEAR (global_load_lds compatible); the 16B source-slot within each
// 64B row is permuted by ((row>>1)&3); reads XOR the same key. All fragment reads
// become <=2-way bank conflicts (free, m136). Read-side key: qx = quad ^ ((c>>1)&3)
// (row bases are all multiples of 32, so (row>>1)&3 == (c>>1)&3 for every fragment).
#define GEMM_MFMA_BODY64(Ab, Bb)                                                \
    bf16x8 af[2], bfr[4];                                                       \
    _Pragma("unroll")                                                           \
    for (int i = 0; i < 2; ++i)                                                 \
      af[i] = *(const bf16x8*)((Ab) + (wr * 32 + i * 16 + c) * 32 + qx * 8);    \
    _Pragma("unroll")                                                           \
    for (int j = 0; j < 4; ++j)                                                 \
      bfr[j] = *(const bf16x8*)((Bb) + (wc * 64 + j * 16 + c) * 32 + qx * 8);   \
    _Pragma("unroll")                                                           \
    for (int i = 0; i < 2; ++i)                                                 \
      _Pragma("unroll")                                                         \
      for (int j = 0; j < 4; ++j)                                               \
        acc[i][j] = __builtin_amdgcn_mfma_f32_16x16x32_bf16(af[i], bfr[j], acc[i][j], 0, 0, 0);

// A f32 in global (reg-staged, pk2-cvt, swizzled ds_write); Bt bf16 via gld16 DMA
// with pre-swizzled per-lane global source (LDS linear).
__device__ __forceinline__ void gemm_f32A_pipe(const float* __restrict__ A,
                                               const u16* __restrict__ Bt,
                                               int m0, int n0, u16* As, u16* Bs,
                                               f32x4 (&acc)[2][4]) {
  const int tid = threadIdx.x;
  const int lane = tid & 63, quad = lane >> 4, c = lane & 15;
  const int wr = (tid >> 6) >> 1, wc = (tid >> 6) & 1;
  const int qx = quad ^ ((c >> 1) & 3);
  const int arow = tid >> 2, aslot = tid & 3;        // 64 rows x 4 slots of 8 f32
  const int awslot = aslot ^ ((arow >> 1) & 3);      // swizzled LDS slot for ds_write
  float4 a0, a1;
#define LOAD_A(kk)                                                     \
  {                                                                    \
    const float* src = A + (size_t)(m0 + arow) * EMB + (kk) + aslot * 8; \
    a0 = *(const float4*)src; a1 = *(const float4*)(src + 4);          \
  }
#define ISSUE_B(kk, buf)                                               \
  _Pragma("unroll")                                                    \
  for (int r = 0; r < 2; ++r) {                                        \
    int bo = r * 4096 + tid * 16;   /* byte off in 128x32u16 (64B/row) */ \
    int brow = bo >> 6, bslot = (bo >> 4) & 3;                         \
    gld16(Bt + (size_t)(n0 + brow) * EMB + (kk) + (bslot ^ ((brow >> 1) & 3)) * 8, \
          Bs + (buf) * 4096 + (bo >> 1));        /* LDS dest linear */ \
  }
  LOAD_A(0); ISSUE_B(0, 0);
  for (int kk = 0; kk < EMB; kk += 32) {
    const int buf = (kk >> 5) & 1;
    {                                             // write A(kk) regs -> As[buf] (swizzled slot)
      uint4 pkv = { pk2(a0.x, a0.y), pk2(a0.z, a0.w),
                    pk2(a1.x, a1.y), pk2(a1.z, a1.w) };
      *(uint4*)(As + buf * 2048 + arow * 32 + awslot * 8) = pkv;
    }
    __syncthreads();                              // drains B(kk) DMA + A writes
    if (kk + 32 < EMB) { LOAD_A(kk + 32); ISSUE_B(kk + 32, buf ^ 1); }
    const u16* Ab = As + buf * 2048;
    const u16* Bb = Bs + buf * 4096;
    GEMM_MFMA_BODY64(Ab, Bb)
  }
#undef LOAD_A
#undef ISSUE_B
}

// Both operands bf16 via gld16 DMA, pre-swizzled sources.
__device__ __forceinline__ void gemm_bf16A_pipe(const u16* __restrict__ A,
                                                const u16* __restrict__ Bt,
                                                int m0, int n0, u16* As, u16* Bs,
                                                f32x4 (&acc)[2][4]) {
  const int tid = threadIdx.x;
  const int lane = tid & 63, quad = lane >> 4, c = lane & 15;
  const int wr = (tid >> 6) >> 1, wc = (tid >> 6) & 1;
  const int qx = quad ^ ((c >> 1) & 3);
#define ISSUE_AB(kk, buf)                                              \
  {                                                                    \
    int arow_ = tid >> 2, aslot_ = tid & 3;                            \
    gld16(A + (size_t)(m0 + arow_) * EMB + (kk) + (aslot_ ^ ((arow_ >> 1) & 3)) * 8, \
          As + (buf) * 2048 + tid * 8);                                \
    _Pragma("unroll")                                                  \
    for (int r = 0; r < 2; ++r) {                                      \
      int bo = r * 4096 + tid * 16;                                    \
      int brow = bo >> 6, bslot = (bo >> 4) & 3;                       \
      gld16(Bt + (size_t)(n0 + brow) * EMB + (kk) + (bslot ^ ((brow >> 1) & 3)) * 8, \
            Bs + (buf) * 4096 + (bo >> 1));                            \
    }                                                                  \
  }
  ISSUE_AB(0, 0);
  for (int kk = 0; kk < EMB; kk += 32) {
    const int buf = (kk >> 5) & 1;
    __syncthreads();                              // drains DMA(kk)
    if (kk + 32 < EMB) { ISSUE_AB(kk + 32, buf ^ 1); }
    const u16* Ab = As + buf * 2048;
    const u16* Bb = Bs + buf * 4096;
    GEMM_MFMA_BODY64(Ab, Bb)
  }
#undef ISSUE_AB
}

// z=0: Q -> Qp[b,s,h*64+d]; z=1: K -> Kp same; z=2: V -> Vt[bh][d][t]
// 1-D grid 1152, XCD-panel swizzle: each XCD owns 24 A-panels x 6 n-tiles.
__launch_bounds__(256, 4)
__global__ void gemm_qkv(const float* __restrict__ q, const float* __restrict__ k,
                         const float* __restrict__ v, const u16* __restrict__ wt3,
                         u16* __restrict__ Qp, u16* __restrict__ Kp, u16* __restrict__ Vt) {
  __shared__ __align__(16) u16 As[2 * 64 * 32];    // 8 KB dbuf
  __shared__ __align__(16) u16 Bs[2 * 128 * 32];   // 16 KB dbuf
  const int id = blockIdx.x;                 // 0..1151
  const int xcd = id & 7, s = id >> 3;       // s: 0..143
  const int panel = xcd * 24 + s / 6;        // 0..191 (z*64 + mtile)
  const int ntile = s - (s / 6) * 6;
  const int z = panel >> 6, mt = panel & 63;
  const int m0 = mt * 64, n0 = ntile * 128;
  const float* A = z == 0 ? q : (z == 1 ? k : v);
  const u16* Bt = wt3 + (size_t)z * EMB * EMB;
  f32x4 acc[2][4];
  const f32x4 fz = {0.f, 0.f, 0.f, 0.f};
#pragma unroll
  for (int i = 0; i < 2; ++i)
#pragma unroll
    for (int j = 0; j < 4; ++j) acc[i][j] = fz;
  gemm_f32A_pipe(A, Bt, m0, n0, As, Bs, acc);
  const int tid = threadIdx.x, lane = tid & 63, quad = lane >> 4, c = lane & 15;
  const int wr = (tid >> 6) >> 1, wc = (tid >> 6) & 1;
  if (z < 2) {
    u16* C = z == 0 ? Qp : Kp;
#pragma unroll
    for (int i = 0; i < 2; ++i)
#pragma unroll
      for (int j = 0; j < 4; ++j) {
        int row = m0 + wr * 32 + i * 16 + quad * 4;
        int col = n0 + wc * 64 + j * 16 + c;
#pragma unroll
        for (int r = 0; r < 4; r += 2) {
          uint32_t d = pk2(acc[i][j][r], acc[i][j][r + 1]);
          C[(size_t)(row + r) * EMB + col] = (u16)d;
          C[(size_t)(row + r + 1) * EMB + col] = (u16)(d >> 16);
        }
      }
  } else {
#pragma unroll
    for (int i = 0; i < 2; ++i)
#pragma unroll
      for (int j = 0; j < 4; ++j) {
        int row = m0 + wr * 32 + i * 16 + quad * 4;   // + r -> consecutive s
        int col = n0 + wc * 64 + j * 16 + c;          // n = h*64+d
        int b = row >> 11, ss = row & 2047;
        int h = col >> 6, d = col & 63;
        uint2 pk = { pk2(acc[i][j][0], acc[i][j][1]), pk2(acc[i][j][2], acc[i][j][3]) };
        *(uint2*)(Vt + ((size_t)(b * NH + h) * DK + d) * SS + ss) = pk;
      }
  }
}

// 1-D grid 384, XCD-panel swizzle: each XCD owns 8 A-panels x 6 n-tiles.
__launch_bounds__(256, 4)
__global__ void gemm_out(const u16* __restrict__ A, const u16* __restrict__ Bt,
                         float* __restrict__ C) {
  __shared__ __align__(16) u16 As[2 * 64 * 32];
  __shared__ __align__(16) u16 Bs[2 * 128 * 32];
  const int id = blockIdx.x;                 // 0..383
  const int xcd = id & 7, s = id >> 3;       // s: 0..47
  const int panel = xcd * 8 + s / 6;         // 0..63
  const int ntile = s - (s / 6) * 6;
  const int m0 = panel * 64, n0 = ntile * 128;
  f32x4 acc[2][4];
  const f32x4 fz = {0.f, 0.f, 0.f, 0.f};
#pragma unroll
  for (int i = 0; i < 2; ++i)
#pragma unroll
    for (int j = 0; j < 4; ++j) acc[i][j] = fz;
  gemm_bf16A_pipe(A, Bt, m0, n0, As, Bs, acc);
  const int tid = threadIdx.x, lane = tid & 63, quad = lane >> 4, c = lane & 15;
  const int wr = (tid >> 6) >> 1, wc = (tid >> 6) & 1;
#pragma unroll
  for (int i = 0; i < 2; ++i)
#pragma unroll
    for (int j = 0; j < 4; ++j)
#pragma unroll
      for (int r = 0; r < 4; ++r) {
        int row = m0 + wr * 32 + i * 16 + quad * 4 + r;
        int col = n0 + wc * 64 + j * 16 + c;
        C[(size_t)row * EMB + col] = acc[i][j][r];   // raw fp32
      }
}

// ---------------- flash attention v6: 32x32 swapped MFMA, in-register softmax ----------------
// Grid 768 (1D, XCD-swizzled): block = (bh, 64-q tile). 8 waves = (wq2: q 32-group) x (th: t slice).
__launch_bounds__(512, 4)
__global__ void attn(const u16* __restrict__ Qp, const u16* __restrict__ Kp,
                     const u16* __restrict__ Vt, const uint64_t* __restrict__ MW,
                     u16* __restrict__ AO) {
  // Ks: [2][128 t][72]  (18432 u16)   Vs: [2][64 d][136] (17408 u16)  = 71680 B
  __shared__ __align__(16) u16 sm[2 * 128 * 72 + 2 * 64 * 136];
  u16* Ks0 = sm;
  u16* Vs0 = sm + 2 * 128 * 72;

  const int tid = threadIdx.x, lane = tid & 63;
  const int c = lane & 31, hi = lane >> 5;
  const int w = tid >> 6;
  const int wq2 = w >> 2, th = w & 3;

  // XCD swizzle: blockIdx.x % 8 = XCD -> all 32 q-tiles of a head stay on one XCD (K/V L2-resident)
  const int wid = blockIdx.x;
  const int xcd = wid & 7, slot = wid >> 3;        // slot 0..95
  const int bh = xcd + 8 * (slot >> 5);            // 0..23
  const int mtile = slot & 31;
  const int b = bh / NH, h = bh - b * NH;
  const int m0 = mtile * 64;

  const size_t qkbase = (size_t)b * SS * EMB + (size_t)h * DK;
  const size_t vtbase = (size_t)bh * DK * SS;

  // Q fragments (B-operand): lane holds Q[q = m0+wq2*32+c][k = ks*16 + hi*8 + e]
  bf16x8 aq[4];
  {
    const u16* qr = Qp + qkbase + (size_t)(m0 + wq2 * 32 + c) * EMB + hi * 8;
    aq[0] = *(const bf16x8*)(qr);
    aq[1] = *(const bf16x8*)(qr + 16);
    aq[2] = *(const bf16x8*)(qr + 32);
    aq[3] = *(const bf16x8*)(qr + 48);
  }

  // staging: K tile 128x64, V^T tile 64x128 -> 32B per thread each array
  const int srK = tid >> 2, scK = (tid & 3) * 16;
  const int srV = tid >> 3, scV = (tid & 7) * 16;
  const u16* gK = Kp + qkbase + (size_t)srK * EMB + scK;
  const u16* gV = Vt + vtbase + (size_t)srV * SS + scV;
  bf16x8 kr0, kr1, vr0, vr1;
#define LOADKV(t0) {                                             \
    const u16* gk_ = gK + (size_t)(t0) * EMB;                    \
    kr0 = *(const bf16x8*)gk_; kr1 = *(const bf16x8*)(gk_ + 8);  \
    const u16* gv_ = gV + (t0);                                  \
    vr0 = *(const bf16x8*)gv_; vr1 = *(const bf16x8*)(gv_ + 8); }
#define STOREKV(buf) {                                           \
    u16* ks_ = Ks0 + (buf) * (128 * 72) + srK * 72 + scK;        \
    *(bf16x8*)ks_ = kr0; *(bf16x8*)(ks_ + 8) = kr1;              \
    u16* vs_ = Vs0 + (buf) * (64 * 136) + srV * 136 + scV;       \
    *(bf16x8*)vs_ = vr0; *(bf16x8*)(vs_ + 8) = vr1; }

  // wave-uniform mask word base (scalar loads)
  const int thu = __builtin_amdgcn_readfirstlane(th);
  const int qgu = __builtin_amdgcn_readfirstlane(mtile * 2 + wq2);
  const uint64_t* mwb = MW + (((size_t)b * 64 + qgu) * 64) * 16 + thu * 16;
#define LOADMSK(m, it) {                                         \
    const uint64_t* mp_ = mwb + (size_t)(it) * 64;               \
    _Pragma("unroll")                                            \
    for (int r_ = 0; r_ < 16; ++r_) m[r_] = mp_[r_]; }

  float fNEG = -1e9f, fM0 = -M0;
  float lr = 0.f;
  f32x16 o0, o1;
#pragma unroll
  for (int r_ = 0; r_ < 16; ++r_) { o0[r_] = 0.f; o1[r_] = 0.f; }

  uint64_t mA[16], mB[16];
  LOADKV(0); LOADMSK(mA, 0);

#define BODY(it, buf, mc, mn) {                                                   \
    STOREKV(buf);                                                                 \
    __syncthreads();                                                              \
    if ((it) < 15) { LOADKV(((it) + 1) * 128); LOADMSK(mn, (it) + 1); }           \
    /* C-init: s[r] = maskbit ? -M0 : -1e9  (one cndmask/elem, SGPR-pair mask) */ \
    f32x16 s;                                                                     \
    _Pragma("unroll")                                                             \
    for (int r_ = 0; r_ < 16; ++r_) {                                             \
      float t_;                                                                   \
      asm("v_cndmask_b32 %0, %1, %2, %3"                                          \
          : "=v"(t_) : "v"(fNEG), "v"(fM0), "s"(mc[r_]));                         \
      s[r_] = t_;                                                                 \
    }                                                                             \
    /* S^T = K * Q^T over k=64 (4 chunks) */                                      \
    const u16* kb_ = Ks0 + (buf) * (128 * 72) + (th * 32 + c) * 72 + hi * 8;      \
    _Pragma("unroll")                                                             \
    for (int ks_ = 0; ks_ < 4; ++ks_) {                                           \
      bf16x8 kf_ = *(const bf16x8*)(kb_ + ks_ * 16);                              \
      s = __builtin_amdgcn_mfma_f32_32x32x16_bf16(kf_, aq[ks_], s, 0, 0, 0);      \
    }                                                                             \
    /* p = exp2(s); masked entries -> exp2(-1e9) = 0 */                           \
    _Pragma("unroll")                                                             \
    for (int r_ = 0; r_ < 16; ++r_) s[r_] = __builtin_amdgcn_exp2f(s[r_]);        \
    lr += ((s[0] + s[1]) + (s[2] + s[3])) + ((s[4] + s[5]) + (s[6] + s[7]))       \
        + ((s[8] + s[9]) + (s[10] + s[11])) + ((s[12] + s[13]) + (s[14] + s[15]));\
    /* in-register P -> PV B-frags: 8 pk2 + 4 permlane32_swap */                  \
    uint32_t x0 = pk2(s[0], s[1]),  x1 = pk2(s[2], s[3]);                         \
    uint32_t y0 = pk2(s[4], s[5]),  y1 = pk2(s[6], s[7]);                         \
    uint32_t z0 = pk2(s[8], s[9]),  z1 = pk2(s[10], s[11]);                       \
    uint32_t w0 = pk2(s[12], s[13]), w1 = pk2(s[14], s[15]);                      \
    asm("v_permlane32_swap_b32 %0, %1" : "+v"(x0), "+v"(y0));                     \
    asm("v_permlane32_swap_b32 %0, %1" : "+v"(x1), "+v"(y1));                     \
    asm("v_permlane32_swap_b32 %0, %1" : "+v"(z0), "+v"(w0));                     \
    asm("v_permlane32_swap_b32 %0, %1" : "+v"(z1), "+v"(w1));                     \
    bf16x8 pa0, pa1;                                                              \
    { union { uint32_t u[4]; bf16x8 v; } cv;                                      \
      cv.u[0] = x0; cv.u[1] = x1; cv.u[2] = y0; cv.u[3] = y1; pa0 = cv.v;         \
      cv.u[0] = z0; cv.u[1] = z1; cv.u[2] = w0; cv.u[3] = w1; pa1 = cv.v; }       \
    /* O^T += V^T * P^T : 2 d-groups x 2 t-chunks */                              \
    const u16* vb_ = Vs0 + (buf) * (64 * 136) + c * 136 + th * 32 + hi * 8;       \
    {                                                                             \
      bf16x8 vf_;                                                                 \
      vf_ = *(const bf16x8*)(vb_);                                                \
      o0 = __builtin_amdgcn_mfma_f32_32x32x16_bf16(vf_, pa0, o0, 0, 0, 0);        \
      vf_ = *(const bf16x8*)(vb_ + 16);                                           \
      o0 = __builtin_amdgcn_mfma_f32_32x32x16_bf16(vf_, pa1, o0, 0, 0, 0);        \
      vf_ = *(const bf16x8*)(vb_ + 32 * 136);                                     \
      o1 = __builtin_amdgcn_mfma_f32_32x32x16_bf16(vf_, pa0, o1, 0, 0, 0);        \
      vf_ = *(const bf16x8*)(vb_ + 32 * 136 + 16);                                \
      o1 = __builtin_amdgcn_mfma_f32_32x32x16_bf16(vf_, pa1, o1, 0, 0, 0);        \
    } }

  for (int i2 = 0; i2 < 8; ++i2) {
    BODY(i2 * 2,     0, mA, mB)
    BODY(i2 * 2 + 1, 1, mB, mA)
  }
#undef BODY
#undef LOADKV
#undef STOREKV
#undef LOADMSK

  // ---- cross-th reduction: partial O^T (f32) + partial l through LDS ----
  lr += __shfl_xor(lr, 32);                 // combine hi halves -> per-row partial for this th
  __syncthreads();                          // all waves done with Ks/Vs
  float* Of = (float*)sm;                   // [4 th][64 row][65]   (66560 B)
  float* Lf = (float*)sm + 4 * 64 * 65;     // [64 row][4 th]       (+1024 B) = 67584 <= 71680
  {
    int row = wq2 * 32 + c;
#pragma unroll
    for (int r_ = 0; r_ < 16; ++r_) {
      int d = (r_ & 3) + 8 * (r_ >> 2) + 4 * hi;
      Of[(th * 64 + row) * 65 + d]      = o0[r_];
      Of[(th * 64 + row) * 65 + 32 + d] = o1[r_];
    }
    if (hi == 0) Lf[row * 4 + th] = lr;
  }
  __syncthreads();
  {
    int qrow = tid >> 3, d0 = (tid & 7) * 8;
    float lt = Lf[qrow * 4 + 0] + Lf[qrow * 4 + 1] + Lf[qrow * 4 + 2] + Lf[qrow * 4 + 3];
    float inv = 1.f / fmaxf(lt, 1e-20f);
    float acc[8];
#pragma unroll
    for (int e = 0; e < 8; ++e) acc[e] = 0.f;
#pragma unroll
    for (int t_ = 0; t_ < 4; ++t_)
#pragma unroll
      for (int e = 0; e < 8; ++e) acc[e] += Of[(t_ * 64 + qrow) * 65 + d0 + e];
    uint32_t dw[4];
#pragma unroll
    for (int e = 0; e < 4; ++e) dw[e] = pk2(acc[2 * e] * inv, acc[2 * e + 1] * inv);
    *(uint4*)(AO + qkbase + (size_t)(m0 + qrow) * EMB + d0) = *(uint4*)dw;
  }
}

extern "C" void kernel_launch(void* const* d_in, const int* in_sizes, int n_in,
                              void* d_out, int out_size, void* d_ws, size_t ws_size,
                              hipStream_t stream) {
  const float* q  = (const float*)d_in[0];
  const float* k  = (const float*)d_in[1];
  const float* v  = (const float*)d_in[2];
  const int* mask = (const int*)d_in[3];
  const float* Wq = (const float*)d_in[4];
  const float* Wk = (const float*)d_in[5];
  const float* Wv = (const float*)d_in[6];
  const float* W  = (const float*)d_in[7];
  float* out = (float*)d_out;

  // d_out (12 MiB) as scratch for Kp + Vt, dead before gemm_out writes.
  u16* Kp = (u16*)d_out;                    // [b,s,h*64+d] bf16
  u16* Vt = (u16*)d_out + 3145728;          // [bh][d][t]   bf16

  // ws: 11.5 MiB
  u16* ws    = (u16*)d_ws;
  u16* Qp    = ws;                          // 3145728 u16; AO aliases
  u16* WqkvT = ws + 3145728;                // 1769472 u16
  u16* WT    = ws + 3145728 + 1769472;      // 589824 u16
  uint64_t* mb64 = (uint64_t*)(ws + 5505024); // 131072 u64 = 1 MiB
  u16* AO = Qp;

  pack_all<<<dim3(11264), 256, 0, stream>>>(Wq, Wk, Wv, W, mask, WqkvT, WT, mb64);
  gemm_qkv<<<dim3(1152), 256, 0, stream>>>(q, k, v, WqkvT, Qp, Kp, Vt);
  attn<<<dim3(768), 512, 0, stream>>>(Qp, Kp, Vt, mb64, AO);
  gemm_out<<<dim3(384), 256, 0, stream>>>(AO, WT, out);
}

// Round 9
// 217.037 us; speedup vs baseline: 1.0664x; 1.0346x over previous
//
#include <hip/hip_runtime.h>
#include <stdint.h>

typedef uint16_t u16;
typedef __attribute__((ext_vector_type(8))) short bf16x8;    // 8 bf16 (4 VGPRs)
typedef __attribute__((ext_vector_type(4))) float f32x4;     // MFMA C/D 16x16
typedef __attribute__((ext_vector_type(16))) float f32x16;   // MFMA C/D 32x32

#define EMB 768
#define NH 12
#define DK 64
#define BB 2
#define SS 2048
#define SCL 0.1803368801111244f   // 0.125 * log2(e)  (folded into Wq at pack time)
#define M0  24.0f                 // fixed softmax offset (log2 domain)

// gfx950 HW packed cvt: lo16 = bf16(a), hi16 = bf16(b), RNE
__device__ __forceinline__ uint32_t pk2(float a, float b) {
  uint32_t d;
  asm("v_cvt_pk_bf16_f32 %0, %1, %2" : "=v"(d) : "v"(a), "v"(b));
  return d;
}

__device__ __forceinline__ void gld16(const u16* g, u16* l) {
  __builtin_amdgcn_global_load_lds((const __attribute__((address_space(1))) void*)g,
                                   (__attribute__((address_space(3))) void*)l, 16, 0, 0);
}

// ---------------- pack kernel: tiled-transpose weights + transposed mask words ----------------
// Weight path (blocks 0..575): 64x64 tile transpose through LDS (pad 65 -> <=2-way banks).
//   blocks 0..431: Wq/Wk/Wv  [h][e][d] -> wqkvT[z][n=h*64+d][e]   (z==0 scaled by SCL)
//   blocks 432..575: W       [e][n]    -> wT[n][e]
// Old path was an uncoalesced stride-256B gather (each lane dragged a 64B line: ~151MB
// effective traffic); this version moves ~19MB fully coalesced.
// Mask path (blocks 576..2623): unchanged ballot repack, u64 word W[b][qg][tg][r], bit l =
//   mask[b][qg*32 + (l&31)][tg*32 + (r&3) + 8*(r>>2) + 4*(l>>5)] != 0
__global__ void pack_all(const float* __restrict__ wq, const float* __restrict__ wk,
                         const float* __restrict__ wv, const float* __restrict__ w,
                         const int* __restrict__ mask,
                         u16* __restrict__ wqkvT, u16* __restrict__ wT,
                         uint64_t* __restrict__ bits) {
  __shared__ float L[65 * 64];              // 16.6 KB transpose tile
  const int bid = blockIdx.x, tid = threadIdx.x;
  if (bid < 576) {
    const float* srcBase;
    int srcRowStride;
    u16* outBase;
    float scale = 1.0f;
    if (bid < 432) {
      int z = bid / 144, rest = bid - z * 144;
      int h = rest / 12, et = rest - h * 12;
      const float* src = z == 0 ? wq : (z == 1 ? wk : wv);
      srcBase = src + (size_t)h * (EMB * DK) + (size_t)(et * 64) * DK;   // + e*64 + d
      srcRowStride = DK;
      outBase = wqkvT + (size_t)z * (EMB * EMB) + (size_t)(h * 64) * EMB + et * 64; // + d*768 + e
      if (z == 0) scale = SCL;
    } else {
      int idx = bid - 432;
      int nt = idx / 12, et = idx - nt * 12;
      srcBase = w + (size_t)(et * 64) * EMB + nt * 64;                   // + e*768 + n'
      srcRowStride = EMB;
      outBase = wT + (size_t)(nt * 64) * EMB + et * 64;                  // + n'*768 + e
    }
    {   // coalesced read: thread = (row e = tid>>2, 16 cols at d0=(tid&3)*16); store L[e + 65*d]
      int e = tid >> 2, d0 = (tid & 3) * 16;
      const float* s_ = srcBase + (size_t)e * srcRowStride + d0;
      float4 v0 = *(const float4*)s_,       v1 = *(const float4*)(s_ + 4);
      float4 v2 = *(const float4*)(s_ + 8), v3 = *(const float4*)(s_ + 12);
      float tv[16] = { v0.x, v0.y, v0.z, v0.w, v1.x, v1.y, v1.z, v1.w,
                       v2.x, v2.y, v2.z, v2.w, v3.x, v3.y, v3.z, v3.w };
#pragma unroll
      for (int j = 0; j < 16; ++j) L[e + 65 * (d0 + j)] = tv[j];
    }
    __syncthreads();
    {   // coalesced write: thread = (out-row d = tid>>2, 16 cols at e0=(tid&3)*16)
      int d = tid >> 2, e0 = (tid & 3) * 16;
      uint32_t pk[8];
#pragma unroll
      for (int j = 0; j < 8; ++j)
        pk[j] = pk2(L[e0 + 2 * j + 65 * d] * scale, L[e0 + 2 * j + 1 + 65 * d] * scale);
      u16* o = outBase + (size_t)d * EMB + e0;
      *(uint4*)o = *(uint4*)pk;
      *(uint4*)(o + 8) = *(uint4*)(pk + 4);
    }
  } else {
    uint32_t widx = (uint32_t)(bid - 576) * 256 + tid;   // [0, 524288): 8192 waves
    uint32_t wv64 = widx >> 6;
    uint32_t lane = widx & 63;
    uint32_t b  = wv64 >> 12;
    uint32_t qg = (wv64 >> 6) & 63;
    uint32_t tg = wv64 & 63;
    uint32_t c = lane & 31, hi = lane >> 5;
    const int* mp = mask + (((size_t)b * 2048 + qg * 32 + c) * 2048 + tg * 32 + hi * 4);
    int4 q0 = *(const int4*)mp;
    int4 q1 = *(const int4*)(mp + 8);
    int4 q2 = *(const int4*)(mp + 16);
    int4 q3 = *(const int4*)(mp + 24);
    uint64_t* wout = bits + (size_t)wv64 * 16;
    unsigned long long ball;
#define BAL(u, arr)                                                   \
    ball = __ballot(arr.x != 0); if (lane == 0) wout[u * 4 + 0] = ball; \
    ball = __ballot(arr.y != 0); if (lane == 0) wout[u * 4 + 1] = ball; \
    ball = __ballot(arr.z != 0); if (lane == 0) wout[u * 4 + 2] = ball; \
    ball = __ballot(arr.w != 0); if (lane == 0) wout[u * 4 + 3] = ball;
    BAL(0, q0) BAL(1, q1) BAL(2, q2) BAL(3, q3)
#undef BAL
  }
}

// ---------------- pipelined GEMM cores (C = A * Bt^T), BK=32, XOR-swizzled ----------------
// R8's proven structure: __syncthreads discipline, LDS dest LINEAR for gld16, global source
// 16B-slot permuted by ((row>>1)&3), reads XOR the same key (qx). 0 bank conflicts (measured).
#define GEMM_MFMA_BODY64(Ab, Bb)                                                \
    bf16x8 af[2], bfr[4];                                                       \
    _Pragma("unroll")                                                           \
    for (int i = 0; i < 2; ++i)                                                 \
      af[i] = *(const bf16x8*)((Ab) + (wr * 32 + i * 16 + c) * 32 + qx * 8);    \
    _Pragma("unroll")                                                           \
    for (int j = 0; j < 4; ++j)                                                 \
      bfr[j] = *(const bf16x8*)((Bb) + (wc * 64 + j * 16 + c) * 32 + qx * 8);   \
    _Pragma("unroll")                                                           \
    for (int i = 0; i < 2; ++i)                                                 \
      _Pragma("unroll")                                                         \
      for (int j = 0; j < 4; ++j)                                               \
        acc[i][j] = __builtin_amdgcn_mfma_f32_16x16x32_bf16(af[i], bfr[j], acc[i][j], 0, 0, 0);

// A f32 in global (reg-staged, pk2-cvt, swizzled ds_write); Bt bf16 via gld16 DMA. 64x128 tile.
__device__ __forceinline__ void gemm_f32A_pipe(const float* __restrict__ A,
                                               const u16* __restrict__ Bt,
                                               int m0, int n0, u16* As, u16* Bs,
                                               f32x4 (&acc)[2][4]) {
  const int tid = threadIdx.x;
  const int lane = tid & 63, quad = lane >> 4, c = lane & 15;
  const int wr = (tid >> 6) >> 1, wc = (tid >> 6) & 1;
  const int qx = quad ^ ((c >> 1) & 3);
  const int arow = tid >> 2, aslot = tid & 3;        // 64 rows x 4 slots of 8 f32
  const int awslot = aslot ^ ((arow >> 1) & 3);      // swizzled LDS slot for ds_write
  float4 a0, a1;
#define LOAD_A(kk)                                                     \
  {                                                                    \
    const float* src = A + (size_t)(m0 + arow) * EMB + (kk) + aslot * 8; \
    a0 = *(const float4*)src; a1 = *(const float4*)(src + 4);          \
  }
#define ISSUE_B(kk, buf)                                               \
  _Pragma("unroll")                                                    \
  for (int r = 0; r < 2; ++r) {                                        \
    int bo = r * 4096 + tid * 16;   /* byte off in 128x32u16 (64B/row) */ \
    int brow = bo >> 6, bslot = (bo >> 4) & 3;                         \
    gld16(Bt + (size_t)(n0 + brow) * EMB + (kk) + (bslot ^ ((brow >> 1) & 3)) * 8, \
          Bs + (buf) * 4096 + (bo >> 1));        /* LDS dest linear */ \
  }
  LOAD_A(0); ISSUE_B(0, 0);
  for (int kk = 0; kk < EMB; kk += 32) {
    const int buf = (kk >> 5) & 1;
    {                                             // write A(kk) regs -> As[buf] (swizzled slot)
      uint4 pkv = { pk2(a0.x, a0.y), pk2(a0.z, a0.w),
                    pk2(a1.x, a1.y), pk2(a1.z, a1.w) };
      *(uint4*)(As + buf * 2048 + arow * 32 + awslot * 8) = pkv;
    }
    __syncthreads();                              // drains B(kk) DMA + A writes
    if (kk + 32 < EMB) { LOAD_A(kk + 32); ISSUE_B(kk + 32, buf ^ 1); }
    const u16* Ab = As + buf * 2048;
    const u16* Bb = Bs + buf * 4096;
    GEMM_MFMA_BODY64(Ab, Bb)
  }
#undef LOAD_A
#undef ISSUE_B
}

// Both operands bf16 via gld16 DMA, pre-swizzled sources. 64x64 tile (acc[2][2]).
__device__ __forceinline__ void gemm_bf16A_pipe64(const u16* __restrict__ A,
                                                  const u16* __restrict__ Bt,
                                                  int m0, int n0, u16* As, u16* Bs,
                                                  f32x4 (&acc)[2][2]) {
  const int tid = threadIdx.x;
  const int lane = tid & 63, quad = lane >> 4, c = lane & 15;
  const int wr = (tid >> 6) >> 1, wc = (tid >> 6) & 1;
  const int qx = quad ^ ((c >> 1) & 3);
#define ISSUE_AB(kk, buf)                                              \
  {                                                                    \
    int arow_ = tid >> 2, aslot_ = tid & 3;                            \
    gld16(A + (size_t)(m0 + arow_) * EMB + (kk) + (aslot_ ^ ((arow_ >> 1) & 3)) * 8, \
          As + (buf) * 2048 + tid * 8);                                \
    int bo = tid * 16;              /* byte off in 64x32u16 (64B/row) */ \
    int brow = bo >> 6, bslot = (bo >> 4) & 3;                         \
    gld16(Bt + (size_t)(n0 + brow) * EMB + (kk) + (bslot ^ ((brow >> 1) & 3)) * 8, \
          Bs + (buf) * 2048 + (bo >> 1));                              \
  }
  ISSUE_AB(0, 0);
  for (int kk = 0; kk < EMB; kk += 32) {
    const int buf = (kk >> 5) & 1;
    __syncthreads();                              // drains DMA(kk)
    if (kk + 32 < EMB) { ISSUE_AB(kk + 32, buf ^ 1); }
    const u16* Ab = As + buf * 2048;
    const u16* Bb = Bs + buf * 2048;
    bf16x8 af[2], bfr[2];
#pragma unroll
    for (int i = 0; i < 2; ++i)
      af[i] = *(const bf16x8*)(Ab + (wr * 32 + i * 16 + c) * 32 + qx * 8);
#pragma unroll
    for (int j = 0; j < 2; ++j)
      bfr[j] = *(const bf16x8*)(Bb + (wc * 32 + j * 16 + c) * 32 + qx * 8);
#pragma unroll
    for (int i = 0; i < 2; ++i)
#pragma unroll
      for (int j = 0; j < 2; ++j)
        acc[i][j] = __builtin_amdgcn_mfma_f32_16x16x32_bf16(af[i], bfr[j], acc[i][j], 0, 0, 0);
  }
#undef ISSUE_AB
}

// z=0: Q -> Qp[b,s,h*64+d]; z=1: K -> Kp same; z=2: V -> Vt[bh][d][t]
// 1-D grid 1152, XCD-panel swizzle: each XCD owns 24 A-panels x 6 n-tiles.
__launch_bounds__(256, 4)
__global__ void gemm_qkv(const float* __restrict__ q, const float* __restrict__ k,
                         const float* __restrict__ v, const u16* __restrict__ wt3,
                         u16* __restrict__ Qp, u16* __restrict__ Kp, u16* __restrict__ Vt) {
  __shared__ __align__(16) u16 As[2 * 64 * 32];    // 8 KB dbuf
  __shared__ __align__(16) u16 Bs[2 * 128 * 32];   // 16 KB dbuf
  const int id = blockIdx.x;                 // 0..1151
  const int xcd = id & 7, s = id >> 3;       // s: 0..143
  const int panel = xcd * 24 + s / 6;        // 0..191 (z*64 + mtile)
  const int ntile = s - (s / 6) * 6;
  const int z = panel >> 6, mt = panel & 63;
  const int m0 = mt * 64, n0 = ntile * 128;
  const float* A = z == 0 ? q : (z == 1 ? k : v);
  const u16* Bt = wt3 + (size_t)z * EMB * EMB;
  f32x4 acc[2][4];
  const f32x4 fz = {0.f, 0.f, 0.f, 0.f};
#pragma unroll
  for (int i = 0; i < 2; ++i)
#pragma unroll
    for (int j = 0; j < 4; ++j) acc[i][j] = fz;
  gemm_f32A_pipe(A, Bt, m0, n0, As, Bs, acc);
  const int tid = threadIdx.x, lane = tid & 63, quad = lane >> 4, c = lane & 15;
  const int wr = (tid >> 6) >> 1, wc = (tid >> 6) & 1;
  if (z < 2) {
    u16* C = z == 0 ? Qp : Kp;
#pragma unroll
    for (int i = 0; i < 2; ++i)
#pragma unroll
      for (int j = 0; j < 4; ++j) {
        int row = m0 + wr * 32 + i * 16 + quad * 4;
        int col = n0 + wc * 64 + j * 16 + c;
#pragma unroll
        for (int r = 0; r < 4; r += 2) {
          uint32_t d = pk2(acc[i][j][r], acc[i][j][r + 1]);
          C[(size_t)(row + r) * EMB + col] = (u16)d;
          C[(size_t)(row + r + 1) * EMB + col] = (u16)(d >> 16);
        }
      }
  } else {
#pragma unroll
    for (int i = 0; i < 2; ++i)
#pragma unroll
      for (int j = 0; j < 4; ++j) {
        int row = m0 + wr * 32 + i * 16 + quad * 4;   // + r -> consecutive s
        int col = n0 + wc * 64 + j * 16 + c;          // n = h*64+d
        int b = row >> 11, ss = row & 2047;
        int h = col >> 6, d = col & 63;
        uint2 pk = { pk2(acc[i][j][0], acc[i][j][1]), pk2(acc[i][j][2], acc[i][j][3]) };
        *(uint2*)(Vt + ((size_t)(b * NH + h) * DK + d) * SS + ss) = pk;
      }
  }
}

// 1-D grid 768 (64x64 tiles -> 3 blocks/CU exact), XCD-panel swizzle: 8 panels x 12 n-tiles/XCD.
__launch_bounds__(256, 4)
__global__ void gemm_out(const u16* __restrict__ A, const u16* __restrict__ Bt,
                         float* __restrict__ C) {
  __shared__ __align__(16) u16 As[2 * 64 * 32];    // 8 KB dbuf
  __shared__ __align__(16) u16 Bs[2 * 64 * 32];    // 8 KB dbuf
  const int id = blockIdx.x;                 // 0..767
  const int xcd = id & 7, s = id >> 3;       // s: 0..95
  const int panel = xcd * 8 + s / 12;        // 0..63
  const int ntile = s - (s / 12) * 12;       // 0..11
  const int m0 = panel * 64, n0 = ntile * 64;
  f32x4 acc[2][2];
  const f32x4 fz = {0.f, 0.f, 0.f, 0.f};
#pragma unroll
  for (int i = 0; i < 2; ++i)
#pragma unroll
    for (int j = 0; j < 2; ++j) acc[i][j] = fz;
  gemm_bf16A_pipe64(A, Bt, m0, n0, As, Bs, acc);
  const int tid = threadIdx.x, lane = tid & 63, quad = lane >> 4, c = lane & 15;
  const int wr = (tid >> 6) >> 1, wc = (tid >> 6) & 1;
#pragma unroll
  for (int i = 0; i < 2; ++i)
#pragma unroll
    for (int j = 0; j < 2; ++j)
#pragma unroll
      for (int r = 0; r < 4; ++r) {
        int row = m0 + wr * 32 + i * 16 + quad * 4 + r;
        int col = n0 + wc * 32 + j * 16 + c;
        C[(size_t)row * EMB + col] = acc[i][j][r];   // raw fp32
      }
}

// ---------------- flash attention v6: 32x32 swapped MFMA, in-register softmax ----------------
// Grid 768 (1D, XCD-swizzled): block = (bh, 64-q tile). 8 waves = (wq2: q 32-group) x (th: t slice).
__launch_bounds__(512, 4)
__global__ void attn(const u16* __restrict__ Qp, const u16* __restrict__ Kp,
                     const u16* __restrict__ Vt, const uint64_t* __restrict__ MW,
                     u16* __restrict__ AO) {
  // Ks: [2][128 t][72]  (18432 u16)   Vs: [2][64 d][136] (17408 u16)  = 71680 B
  __shared__ __align__(16) u16 sm[2 * 128 * 72 + 2 * 64 * 136];
  u16* Ks0 = sm;
  u16* Vs0 = sm + 2 * 128 * 72;

  const int tid = threadIdx.x, lane = tid & 63;
  const int c = lane & 31, hi = lane >> 5;
  const int w = tid >> 6;
  const int wq2 = w >> 2, th = w & 3;

  // XCD swizzle: blockIdx.x % 8 = XCD -> all 32 q-tiles of a head stay on one XCD (K/V L2-resident)
  const int wid = blockIdx.x;
  const int xcd = wid & 7, slot = wid >> 3;        // slot 0..95
  const int bh = xcd + 8 * (slot >> 5);            // 0..23
  const int mtile = slot & 31;
  const int b = bh / NH, h = bh - b * NH;
  const int m0 = mtile * 64;

  const size_t qkbase = (size_t)b * SS * EMB + (size_t)h * DK;
  const size_t vtbase = (size_t)bh * DK * SS;

  // Q fragments (B-operand): lane holds Q[q = m0+wq2*32+c][k = ks*16 + hi*8 + e]
  bf16x8 aq[4];
  {
    const u16* qr = Qp + qkbase + (size_t)(m0 + wq2 * 32 + c) * EMB + hi * 8;
    aq[0] = *(const bf16x8*)(qr);
    aq[1] = *(const bf16x8*)(qr + 16);
    aq[2] = *(const bf16x8*)(qr + 32);
    aq[3] = *(const bf16x8*)(qr + 48);
  }

  // staging: K tile 128x64, V^T tile 64x128 -> 32B per thread each array
  const int srK = tid >> 2, scK = (tid & 3) * 16;
  const int srV = tid >> 3, scV = (tid & 7) * 16;
  const u16* gK = Kp + qkbase + (size_t)srK * EMB + scK;
  const u16* gV = Vt + vtbase + (size_t)srV * SS + scV;
  bf16x8 kr0, kr1, vr0, vr1;
#define LOADKV(t0) {                                             \
    const u16* gk_ = gK + (size_t)(t0) * EMB;                    \
    kr0 = *(const bf16x8*)gk_; kr1 = *(const bf16x8*)(gk_ + 8);  \
    const u16* gv_ = gV + (t0);                                  \
    vr0 = *(const bf16x8*)gv_; vr1 = *(const bf16x8*)(gv_ + 8); }
#define STOREKV(buf) {                                           \
    u16* ks_ = Ks0 + (buf) * (128 * 72) + srK * 72 + scK;        \
    *(bf16x8*)ks_ = kr0; *(bf16x8*)(ks_ + 8) = kr1;              \
    u16* vs_ = Vs0 + (buf) * (64 * 136) + srV * 136 + scV;       \
    *(bf16x8*)vs_ = vr0; *(bf16x8*)(vs_ + 8) = vr1; }

  // wave-uniform mask word base (scalar loads)
  const int thu = __builtin_amdgcn_readfirstlane(th);
  const int qgu = __builtin_amdgcn_readfirstlane(mtile * 2 + wq2);
  const uint64_t* mwb = MW + (((size_t)b * 64 + qgu) * 64) * 16 + thu * 16;
#define LOADMSK(m, it) {                                         \
    const uint64_t* mp_ = mwb + (size_t)(it) * 64;               \
    _Pragma("unroll")                                            \
    for (int r_ = 0; r_ < 16; ++r_) m[r_] = mp_[r_]; }

  float fNEG = -1e9f, fM0 = -M0;
  float lr = 0.f;
  f32x16 o0, o1;
#pragma unroll
  for (int r_ = 0; r_ < 16; ++r_) { o0[r_] = 0.f; o1[r_] = 0.f; }

  uint64_t mA[16], mB[16];
  LOADKV(0); LOADMSK(mA, 0);

#define BODY(it, buf, mc, mn) {                                                   \
    STOREKV(buf);                                                                 \
    __syncthreads();                                                              \
    if ((it) < 15) { LOADKV(((it) + 1) * 128); LOADMSK(mn, (it) + 1); }           \
    /* C-init: s[r] = maskbit ? -M0 : -1e9  (one cndmask/elem, SGPR-pair mask) */ \
    f32x16 s;                                                                     \
    _Pragma("unroll")                                                             \
    for (int r_ = 0; r_ < 16; ++r_) {                                             \
      float t_;                                                                   \
      asm("v_cndmask_b32 %0, %1, %2, %3"                                          \
          : "=v"(t_) : "v"(fNEG), "v"(fM0), "s"(mc[r_]));                         \
      s[r_] = t_;                                                                 \
    }                                                                             \
    /* S^T = K * Q^T over k=64 (4 chunks) */                                      \
    const u16* kb_ = Ks0 + (buf) * (128 * 72) + (th * 32 + c) * 72 + hi * 8;      \
    _Pragma("unroll")                                                             \
    for (int ks_ = 0; ks_ < 4; ++ks_) {                                           \
      bf16x8 kf_ = *(const bf16x8*)(kb_ + ks_ * 16);                              \
      s = __builtin_amdgcn_mfma_f32_32x32x16_bf16(kf_, aq[ks_], s, 0, 0, 0);      \
    }                                                                             \
    /* p = exp2(s); masked entries -> exp2(-1e9) = 0 */                           \
    _Pragma("unroll")                                                             \
    for (int r_ = 0; r_ < 16; ++r_) s[r_] = __builtin_amdgcn_exp2f(s[r_]);        \
    lr += ((s[0] + s[1]) + (s[2] + s[3])) + ((s[4] + s[5]) + (s[6] + s[7]))       \
        + ((s[8] + s[9]) + (s[10] + s[11])) + ((s[12] + s[13]) + (s[14] + s[15]));\
    /* in-register P -> PV B-frags: 8 pk2 + 4 permlane32_swap */                  \
    uint32_t x0 = pk2(s[0], s[1]),  x1 = pk2(s[2], s[3]);                         \
    uint32_t y0 = pk2(s[4], s[5]),  y1 = pk2(s[6], s[7]);                         \
    uint32_t z0 = pk2(s[8], s[9]),  z1 = pk2(s[10], s[11]);                       \
    uint32_t w0 = pk2(s[12], s[13]), w1 = pk2(s[14], s[15]);                      \
    asm("v_permlane32_swap_b32 %0, %1" : "+v"(x0), "+v"(y0));                     \
    asm("v_permlane32_swap_b32 %0, %1" : "+v"(x1), "+v"(y1));                     \
    asm("v_permlane32_swap_b32 %0, %1" : "+v"(z0), "+v"(w0));                     \
    asm("v_permlane32_swap_b32 %0, %1" : "+v"(z1), "+v"(w1));                     \
    bf16x8 pa0, pa1;                                                              \
    { union { uint32_t u[4]; bf16x8 v; } cv;                                      \
      cv.u[0] = x0; cv.u[1] = x1; cv.u[2] = y0; cv.u[3] = y1; pa0 = cv.v;         \
      cv.u[0] = z0; cv.u[1] = z1; cv.u[2] = w0; cv.u[3] = w1; pa1 = cv.v; }       \
    /* O^T += V^T * P^T : 2 d-groups x 2 t-chunks */                              \
    const u16* vb_ = Vs0 + (buf) * (64 * 136) + c * 136 + th * 32 + hi * 8;       \
    {                                                                             \
      bf16x8 vf_;                                                                 \
      vf_ = *(const bf16x8*)(vb_);                                                \
      o0 = __builtin_amdgcn_mfma_f32_32x32x16_bf16(vf_, pa0, o0, 0, 0, 0);        \
      vf_ = *(const bf16x8*)(vb_ + 16);                                           \
      o0 = __builtin_amdgcn_mfma_f32_32x32x16_bf16(vf_, pa1, o0, 0, 0, 0);        \
      vf_ = *(const bf16x8*)(vb_ + 32 * 136);                                     \
      o1 = __builtin_amdgcn_mfma_f32_32x32x16_bf16(vf_, pa0, o1, 0, 0, 0);        \
      vf_ = *(const bf16x8*)(vb_ + 32 * 136 + 16);                                \
      o1 = __builtin_amdgcn_mfma_f32_32x32x16_bf16(vf_, pa1, o1, 0, 0, 0);        \
    } }

  for (int i2 = 0; i2 < 8; ++i2) {
    BODY(i2 * 2,     0, mA, mB)
    BODY(i2 * 2 + 1, 1, mB, mA)
  }
#undef BODY
#undef LOADKV
#undef STOREKV
#undef LOADMSK

  // ---- cross-th reduction: partial O^T (f32) + partial l through LDS ----
  lr += __shfl_xor(lr, 32);                 // combine hi halves -> per-row partial for this th
  __syncthreads();                          // all waves done with Ks/Vs
  float* Of = (float*)sm;                   // [4 th][64 row][65]   (66560 B)
  float* Lf = (float*)sm + 4 * 64 * 65;     // [64 row][4 th]       (+1024 B) = 67584 <= 71680
  {
    int row = wq2 * 32 + c;
#pragma unroll
    for (int r_ = 0; r_ < 16; ++r_) {
      int d = (r_ & 3) + 8 * (r_ >> 2) + 4 * hi;
      Of[(th * 64 + row) * 65 + d]      = o0[r_];
      Of[(th * 64 + row) * 65 + 32 + d] = o1[r_];
    }
    if (hi == 0) Lf[row * 4 + th] = lr;
  }
  __syncthreads();
  {
    int qrow = tid >> 3, d0 = (tid & 7) * 8;
    float lt = Lf[qrow * 4 + 0] + Lf[qrow * 4 + 1] + Lf[qrow * 4 + 2] + Lf[qrow * 4 + 3];
    float inv = 1.f / fmaxf(lt, 1e-20f);
    float acc[8];
#pragma unroll
    for (int e = 0; e < 8; ++e) acc[e] = 0.f;
#pragma unroll
    for (int t_ = 0; t_ < 4; ++t_)
#pragma unroll
      for (int e = 0; e < 8; ++e) acc[e] += Of[(t_ * 64 + qrow) * 65 + d0 + e];
    uint32_t dw[4];
#pragma unroll
    for (int e = 0; e < 4; ++e) dw[e] = pk2(acc[2 * e] * inv, acc[2 * e + 1] * inv);
    *(uint4*)(AO + qkbase + (size_t)(m0 + qrow) * EMB + d0) = *(uint4*)dw;
  }
}

extern "C" void kernel_launch(void* const* d_in, const int* in_sizes, int n_in,
                              void* d_out, int out_size, void* d_ws, size_t ws_size,
                              hipStream_t stream) {
  const float* q  = (const float*)d_in[0];
  const float* k  = (const float*)d_in[1];
  const float* v  = (const float*)d_in[2];
  const int* mask = (const int*)d_in[3];
  const float* Wq = (const float*)d_in[4];
  const float* Wk = (const float*)d_in[5];
  const float* Wv = (const float*)d_in[6];
  const float* W  = (const float*)d_in[7];
  float* out = (float*)d_out;

  // d_out (12 MiB) as scratch for Kp + Vt, dead before gemm_out writes.
  u16* Kp = (u16*)d_out;                    // [b,s,h*64+d] bf16
  u16* Vt = (u16*)d_out + 3145728;          // [bh][d][t]   bf16

  // ws: 11.5 MiB
  u16* ws    = (u16*)d_ws;
  u16* Qp    = ws;                          // 3145728 u16; AO aliases
  u16* WqkvT = ws + 3145728;                // 1769472 u16
  u16* WT    = ws + 3145728 + 1769472;      // 589824 u16
  uint64_t* mb64 = (uint64_t*)(ws + 5505024); // 131072 u64 = 1 MiB
  u16* AO = Qp;

  pack_all<<<dim3(2624), 256, 0, stream>>>(Wq, Wk, Wv, W, mask, WqkvT, WT, mb64);
  gemm_qkv<<<dim3(1152), 256, 0, stream>>>(q, k, v, WqkvT, Qp, Kp, Vt);
  attn<<<dim3(768), 512, 0, stream>>>(Qp, Kp, Vt, mb64, AO);
  gemm_out<<<dim3(768), 256, 0, stream>>>(AO, WT, out);
}

// Round 10
// 209.351 us; speedup vs baseline: 1.1056x; 1.0367x over previous
//
#include <hip/hip_runtime.h>
#include <stdint.h>

typedef uint16_t u16;
typedef __attribute__((ext_vector_type(8))) short bf16x8;    // 8 bf16 (4 VGPRs)
typedef __attribute__((ext_vector_type(4))) float f32x4;     // MFMA C/D 16x16
typedef __attribute__((ext_vector_type(16))) float f32x16;   // MFMA C/D 32x32

#define EMB 768
#define NH 12
#define DK 64
#define BB 2
#define SS 2048
#define SCL 0.1803368801111244f   // 0.125 * log2(e)  (folded into Wq at pack time)
#define M0  24.0f                 // fixed softmax offset (log2 domain)

// gfx950 HW packed cvt: lo16 = bf16(a), hi16 = bf16(b), RNE
__device__ __forceinline__ uint32_t pk2(float a, float b) {
  uint32_t d;
  asm("v_cvt_pk_bf16_f32 %0, %1, %2" : "=v"(d) : "v"(a), "v"(b));
  return d;
}

__device__ __forceinline__ void gld16(const u16* g, u16* l) {
  __builtin_amdgcn_global_load_lds((const __attribute__((address_space(1))) void*)g,
                                   (__attribute__((address_space(3))) void*)l, 16, 0, 0);
}

// ---------------- pack kernel: tiled-transpose weights + transposed mask words ----------------
// Weight path (blocks 0..575): 64x64 tile transpose through LDS (pad 65 -> <=2-way banks).
// Mask path (blocks 576..2623): ballot repack, u64 word W[b][qg][tg][r], bit l =
//   mask[b][qg*32 + (l&31)][tg*32 + (r&3) + 8*(r>>2) + 4*(l>>5)] != 0
__global__ void pack_all(const float* __restrict__ wq, const float* __restrict__ wk,
                         const float* __restrict__ wv, const float* __restrict__ w,
                         const int* __restrict__ mask,
                         u16* __restrict__ wqkvT, u16* __restrict__ wT,
                         uint64_t* __restrict__ bits) {
  __shared__ float L[65 * 64];              // 16.6 KB transpose tile
  const int bid = blockIdx.x, tid = threadIdx.x;
  if (bid < 576) {
    const float* srcBase;
    int srcRowStride;
    u16* outBase;
    float scale = 1.0f;
    if (bid < 432) {
      int z = bid / 144, rest = bid - z * 144;
      int h = rest / 12, et = rest - h * 12;
      const float* src = z == 0 ? wq : (z == 1 ? wk : wv);
      srcBase = src + (size_t)h * (EMB * DK) + (size_t)(et * 64) * DK;   // + e*64 + d
      srcRowStride = DK;
      outBase = wqkvT + (size_t)z * (EMB * EMB) + (size_t)(h * 64) * EMB + et * 64; // + d*768 + e
      if (z == 0) scale = SCL;
    } else {
      int idx = bid - 432;
      int nt = idx / 12, et = idx - nt * 12;
      srcBase = w + (size_t)(et * 64) * EMB + nt * 64;                   // + e*768 + n'
      srcRowStride = EMB;
      outBase = wT + (size_t)(nt * 64) * EMB + et * 64;                  // + n'*768 + e
    }
    {   // coalesced read: thread = (row e = tid>>2, 16 cols at d0=(tid&3)*16); store L[e + 65*d]
      int e = tid >> 2, d0 = (tid & 3) * 16;
      const float* s_ = srcBase + (size_t)e * srcRowStride + d0;
      float4 v0 = *(const float4*)s_,       v1 = *(const float4*)(s_ + 4);
      float4 v2 = *(const float4*)(s_ + 8), v3 = *(const float4*)(s_ + 12);
      float tv[16] = { v0.x, v0.y, v0.z, v0.w, v1.x, v1.y, v1.z, v1.w,
                       v2.x, v2.y, v2.z, v2.w, v3.x, v3.y, v3.z, v3.w };
#pragma unroll
      for (int j = 0; j < 16; ++j) L[e + 65 * (d0 + j)] = tv[j];
    }
    __syncthreads();
    {   // coalesced write: thread = (out-row d = tid>>2, 16 cols at e0=(tid&3)*16)
      int d = tid >> 2, e0 = (tid & 3) * 16;
      uint32_t pk[8];
#pragma unroll
      for (int j = 0; j < 8; ++j)
        pk[j] = pk2(L[e0 + 2 * j + 65 * d] * scale, L[e0 + 2 * j + 1 + 65 * d] * scale);
      u16* o = outBase + (size_t)d * EMB + e0;
      *(uint4*)o = *(uint4*)pk;
      *(uint4*)(o + 8) = *(uint4*)(pk + 4);
    }
  } else {
    uint32_t widx = (uint32_t)(bid - 576) * 256 + tid;   // [0, 524288): 8192 waves
    uint32_t wv64 = widx >> 6;
    uint32_t lane = widx & 63;
    uint32_t b  = wv64 >> 12;
    uint32_t qg = (wv64 >> 6) & 63;
    uint32_t tg = wv64 & 63;
    uint32_t c = lane & 31, hi = lane >> 5;
    const int* mp = mask + (((size_t)b * 2048 + qg * 32 + c) * 2048 + tg * 32 + hi * 4);
    int4 q0 = *(const int4*)mp;
    int4 q1 = *(const int4*)(mp + 8);
    int4 q2 = *(const int4*)(mp + 16);
    int4 q3 = *(const int4*)(mp + 24);
    uint64_t* wout = bits + (size_t)wv64 * 16;
    unsigned long long ball;
#define BAL(u, arr)                                                   \
    ball = __ballot(arr.x != 0); if (lane == 0) wout[u * 4 + 0] = ball; \
    ball = __ballot(arr.y != 0); if (lane == 0) wout[u * 4 + 1] = ball; \
    ball = __ballot(arr.z != 0); if (lane == 0) wout[u * 4 + 2] = ball; \
    ball = __ballot(arr.w != 0); if (lane == 0) wout[u * 4 + 3] = ball;
    BAL(0, q0) BAL(1, q1) BAL(2, q2) BAL(3, q3)
#undef BAL
  }
}

// ---------------- pipelined GEMM cores (C = A * Bt^T), BK=64, 8-slot XOR swizzle ----------------
// R7/R8's proven discipline (__syncthreads, LDS dest LINEAR for gld16, pre-swizzled global
// source) scaled to BK=64: 12 K-steps (half the barrier/drain exposures), 16 MFMA/step.
// Rows are 128B = 8 slots of 16B; involution slot ^= (row&7). Every fragment read lands
// 2 lanes/slot -> conflict-free (m136). Read key qx8 = (ks*4+quad) ^ (c&7) since all
// fragment row bases are multiples of 8 (row&7 == c&7).

// gemm_qkv core: A f32 global->regs (pk2-cvt, swizzled ds_write); Bt bf16 via gld16. 64x128 tile.
__device__ __forceinline__ void gemm_f32A_pipe(const float* __restrict__ A,
                                               const u16* __restrict__ Bt,
                                               int m0, int n0, u16* As, u16* Bs,
                                               f32x4 (&acc)[2][4]) {
  const int tid = threadIdx.x;
  const int lane = tid & 63, quad = lane >> 4, c = lane & 15;
  const int wr = (tid >> 6) >> 1, wc = (tid >> 6) & 1;
  const int arow = tid >> 2, a4 = tid & 3;          // A: 64 rows x 64 f32, 16 f32/thread
  const int s0 = (2 * a4) ^ (arow & 7);             // swizzled 16B-slot for lo 8 cols
  const int s1 = (2 * a4 + 1) ^ (arow & 7);         // swizzled 16B-slot for hi 8 cols
  float4 a0, a1, a2, a3;
#define LOAD_A(kk)                                                     \
  {                                                                    \
    const float* src = A + (size_t)(m0 + arow) * EMB + (kk) + a4 * 16; \
    a0 = *(const float4*)src;       a1 = *(const float4*)(src + 4);    \
    a2 = *(const float4*)(src + 8); a3 = *(const float4*)(src + 12);   \
  }
#define ISSUE_B(kk, buf)                                               \
  _Pragma("unroll")                                                    \
  for (int r = 0; r < 4; ++r) {                                        \
    int bo = r * 4096 + tid * 16;   /* byte off in 128x64u16 (128B/row) */ \
    int brow = bo >> 7, bslot = (bo >> 4) & 7;                         \
    gld16(Bt + (size_t)(n0 + brow) * EMB + (kk) + (bslot ^ (brow & 7)) * 8, \
          Bs + (buf) * 8192 + (bo >> 1));        /* LDS dest linear */ \
  }
  LOAD_A(0); ISSUE_B(0, 0);
  for (int kk = 0; kk < EMB; kk += 64) {
    const int buf = (kk >> 6) & 1;
    {                                             // write A(kk) regs -> As[buf] (swizzled slots)
      uint4 p0 = { pk2(a0.x, a0.y), pk2(a0.z, a0.w), pk2(a1.x, a1.y), pk2(a1.z, a1.w) };
      uint4 p1 = { pk2(a2.x, a2.y), pk2(a2.z, a2.w), pk2(a3.x, a3.y), pk2(a3.z, a3.w) };
      *(uint4*)(As + buf * 4096 + arow * 64 + s0 * 8) = p0;
      *(uint4*)(As + buf * 4096 + arow * 64 + s1 * 8) = p1;
    }
    __syncthreads();                              // drains B(kk) DMA + A writes
    if (kk + 64 < EMB) { LOAD_A(kk + 64); ISSUE_B(kk + 64, buf ^ 1); }
    const u16* Ab = As + buf * 4096;
    const u16* Bb = Bs + buf * 8192;
#pragma unroll
    for (int ks = 0; ks < 2; ++ks) {
      const int qx8 = (ks * 4 + quad) ^ (c & 7);
      bf16x8 af[2], bfr[4];
#pragma unroll
      for (int i = 0; i < 2; ++i)
        af[i] = *(const bf16x8*)(Ab + (wr * 32 + i * 16 + c) * 64 + qx8 * 8);
#pragma unroll
      for (int j = 0; j < 4; ++j)
        bfr[j] = *(const bf16x8*)(Bb + (wc * 64 + j * 16 + c) * 64 + qx8 * 8);
#pragma unroll
      for (int i = 0; i < 2; ++i)
#pragma unroll
        for (int j = 0; j < 4; ++j)
          acc[i][j] = __builtin_amdgcn_mfma_f32_16x16x32_bf16(af[i], bfr[j], acc[i][j], 0, 0, 0);
    }
  }
#undef LOAD_A
#undef ISSUE_B
}

// gemm_out core: both operands bf16 via gld16, pre-swizzled sources. 64x64 tile, acc[2][2].
__device__ __forceinline__ void gemm_bf16A_pipe(const u16* __restrict__ A,
                                                const u16* __restrict__ Bt,
                                                int m0, int n0, u16* As, u16* Bs,
                                                f32x4 (&acc)[2][2]) {
  const int tid = threadIdx.x;
  const int lane = tid & 63, quad = lane >> 4, c = lane & 15;
  const int wr = (tid >> 6) >> 1, wc = (tid >> 6) & 1;
#define ISSUE_AB(kk, buf)                                              \
  {                                                                    \
    _Pragma("unroll")                                                  \
    for (int r = 0; r < 2; ++r) {   /* A: 64x64u16 = 8KB/buf */        \
      int ao = r * 4096 + tid * 16;                                    \
      int arw = ao >> 7, asl = (ao >> 4) & 7;                          \
      gld16(A + (size_t)(m0 + arw) * EMB + (kk) + (asl ^ (arw & 7)) * 8, \
            As + (buf) * 4096 + (ao >> 1));                            \
    }                                                                  \
    _Pragma("unroll")                                                  \
    for (int r = 0; r < 2; ++r) {   /* B: 64x64u16 = 8KB/buf */        \
      int bo = r * 4096 + tid * 16;                                    \
      int brw = bo >> 7, bsl = (bo >> 4) & 7;                          \
      gld16(Bt + (size_t)(n0 + brw) * EMB + (kk) + (bsl ^ (brw & 7)) * 8, \
            Bs + (buf) * 4096 + (bo >> 1));                            \
    }                                                                  \
  }
  ISSUE_AB(0, 0);
  for (int kk = 0; kk < EMB; kk += 64) {
    const int buf = (kk >> 6) & 1;
    __syncthreads();                              // drains DMA(kk)
    if (kk + 64 < EMB) { ISSUE_AB(kk + 64, buf ^ 1); }
    const u16* Ab = As + buf * 4096;
    const u16* Bb = Bs + buf * 4096;
#pragma unroll
    for (int ks = 0; ks < 2; ++ks) {
      const int qx8 = (ks * 4 + quad) ^ (c & 7);
      bf16x8 af[2], bfr[2];
#pragma unroll
      for (int i = 0; i < 2; ++i)
        af[i] = *(const bf16x8*)(Ab + (wr * 32 + i * 16 + c) * 64 + qx8 * 8);
#pragma unroll
      for (int j = 0; j < 2; ++j)
        bfr[j] = *(const bf16x8*)(Bb + (wc * 32 + j * 16 + c) * 64 + qx8 * 8);
#pragma unroll
      for (int i = 0; i < 2; ++i)
#pragma unroll
        for (int j = 0; j < 2; ++j)
          acc[i][j] = __builtin_amdgcn_mfma_f32_16x16x32_bf16(af[i], bfr[j], acc[i][j], 0, 0, 0);
    }
  }
#undef ISSUE_AB
}

// z=0: Q -> Qp[b,s,h*64+d]; z=1: K -> Kp same; z=2: V -> Vt[bh][d][t]
// 1-D grid 1152, XCD-panel swizzle: each XCD owns 24 A-panels x 6 n-tiles.
__launch_bounds__(256, 3)
__global__ void gemm_qkv(const float* __restrict__ q, const float* __restrict__ k,
                         const float* __restrict__ v, const u16* __restrict__ wt3,
                         u16* __restrict__ Qp, u16* __restrict__ Kp, u16* __restrict__ Vt) {
  __shared__ __align__(16) u16 As[2 * 64 * 64];    // 16 KB dbuf
  __shared__ __align__(16) u16 Bs[2 * 128 * 64];   // 32 KB dbuf
  const int id = blockIdx.x;                 // 0..1151
  const int xcd = id & 7, s = id >> 3;       // s: 0..143
  const int panel = xcd * 24 + s / 6;        // 0..191 (z*64 + mtile)
  const int ntile = s - (s / 6) * 6;
  const int z = panel >> 6, mt = panel & 63;
  const int m0 = mt * 64, n0 = ntile * 128;
  const float* A = z == 0 ? q : (z == 1 ? k : v);
  const u16* Bt = wt3 + (size_t)z * EMB * EMB;
  f32x4 acc[2][4];
  const f32x4 fz = {0.f, 0.f, 0.f, 0.f};
#pragma unroll
  for (int i = 0; i < 2; ++i)
#pragma unroll
    for (int j = 0; j < 4; ++j) acc[i][j] = fz;
  gemm_f32A_pipe(A, Bt, m0, n0, As, Bs, acc);
  const int tid = threadIdx.x, lane = tid & 63, quad = lane >> 4, c = lane & 15;
  const int wr = (tid >> 6) >> 1, wc = (tid >> 6) & 1;
  if (z < 2) {
    u16* C = z == 0 ? Qp : Kp;
#pragma unroll
    for (int i = 0; i < 2; ++i)
#pragma unroll
      for (int j = 0; j < 4; ++j) {
        int row = m0 + wr * 32 + i * 16 + quad * 4;
        int col = n0 + wc * 64 + j * 16 + c;
#pragma unroll
        for (int r = 0; r < 4; r += 2) {
          uint32_t d = pk2(acc[i][j][r], acc[i][j][r + 1]);
          C[(size_t)(row + r) * EMB + col] = (u16)d;
          C[(size_t)(row + r + 1) * EMB + col] = (u16)(d >> 16);
        }
      }
  } else {
#pragma unroll
    for (int i = 0; i < 2; ++i)
#pragma unroll
      for (int j = 0; j < 4; ++j) {
        int row = m0 + wr * 32 + i * 16 + quad * 4;   // + r -> consecutive s
        int col = n0 + wc * 64 + j * 16 + c;          // n = h*64+d
        int b = row >> 11, ss = row & 2047;
        int h = col >> 6, d = col & 63;
        uint2 pk = { pk2(acc[i][j][0], acc[i][j][1]), pk2(acc[i][j][2], acc[i][j][3]) };
        *(uint2*)(Vt + ((size_t)(b * NH + h) * DK + d) * SS + ss) = pk;
      }
  }
}

// 1-D grid 768 (64x64 tiles -> 3 blocks/CU exact), XCD-panel swizzle: 8 panels x 12 n-tiles/XCD.
__launch_bounds__(256, 4)
__global__ void gemm_out(const u16* __restrict__ A, const u16* __restrict__ Bt,
                         float* __restrict__ C) {
  __shared__ __align__(16) u16 As[2 * 64 * 64];    // 16 KB dbuf
  __shared__ __align__(16) u16 Bs[2 * 64 * 64];    // 16 KB dbuf
  const int id = blockIdx.x;                 // 0..767
  const int xcd = id & 7, s = id >> 3;       // s: 0..95
  const int panel = xcd * 8 + s / 12;        // 0..63
  const int ntile = s - (s / 12) * 12;       // 0..11
  const int m0 = panel * 64, n0 = ntile * 64;
  f32x4 acc[2][2];
  const f32x4 fz = {0.f, 0.f, 0.f, 0.f};
#pragma unroll
  for (int i = 0; i < 2; ++i)
#pragma unroll
    for (int j = 0; j < 2; ++j) acc[i][j] = fz;
  gemm_bf16A_pipe(A, Bt, m0, n0, As, Bs, acc);
  const int tid = threadIdx.x, lane = tid & 63, quad = lane >> 4, c = lane & 15;
  const int wr = (tid >> 6) >> 1, wc = (tid >> 6) & 1;
#pragma unroll
  for (int i = 0; i < 2; ++i)
#pragma unroll
    for (int j = 0; j < 2; ++j)
#pragma unroll
      for (int r = 0; r < 4; ++r) {
        int row = m0 + wr * 32 + i * 16 + quad * 4 + r;
        int col = n0 + wc * 32 + j * 16 + c;
        C[(size_t)row * EMB + col] = acc[i][j][r];   // raw fp32
      }
}

// ---------------- flash attention v6: 32x32 swapped MFMA, in-register softmax ----------------
// Grid 768 (1D, XCD-swizzled): block = (bh, 64-q tile). 8 waves = (wq2: q 32-group) x (th: t slice).
__launch_bounds__(512, 4)
__global__ void attn(const u16* __restrict__ Qp, const u16* __restrict__ Kp,
                     const u16* __restrict__ Vt, const uint64_t* __restrict__ MW,
                     u16* __restrict__ AO) {
  // Ks: [2][128 t][72]  (18432 u16)   Vs: [2][64 d][136] (17408 u16)  = 71680 B
  __shared__ __align__(16) u16 sm[2 * 128 * 72 + 2 * 64 * 136];
  u16* Ks0 = sm;
  u16* Vs0 = sm + 2 * 128 * 72;

  const int tid = threadIdx.x, lane = tid & 63;
  const int c = lane & 31, hi = lane >> 5;
  const int w = tid >> 6;
  const int wq2 = w >> 2, th = w & 3;

  // XCD swizzle: blockIdx.x % 8 = XCD -> all 32 q-tiles of a head stay on one XCD (K/V L2-resident)
  const int wid = blockIdx.x;
  const int xcd = wid & 7, slot = wid >> 3;        // slot 0..95
  const int bh = xcd + 8 * (slot >> 5);            // 0..23
  const int mtile = slot & 31;
  const int b = bh / NH, h = bh - b * NH;
  const int m0 = mtile * 64;

  const size_t qkbase = (size_t)b * SS * EMB + (size_t)h * DK;
  const size_t vtbase = (size_t)bh * DK * SS;

  // Q fragments (B-operand): lane holds Q[q = m0+wq2*32+c][k = ks*16 + hi*8 + e]
  bf16x8 aq[4];
  {
    const u16* qr = Qp + qkbase + (size_t)(m0 + wq2 * 32 + c) * EMB + hi * 8;
    aq[0] = *(const bf16x8*)(qr);
    aq[1] = *(const bf16x8*)(qr + 16);
    aq[2] = *(const bf16x8*)(qr + 32);
    aq[3] = *(const bf16x8*)(qr + 48);
  }

  // staging: K tile 128x64, V^T tile 64x128 -> 32B per thread each array
  const int srK = tid >> 2, scK = (tid & 3) * 16;
  const int srV = tid >> 3, scV = (tid & 7) * 16;
  const u16* gK = Kp + qkbase + (size_t)srK * EMB + scK;
  const u16* gV = Vt + vtbase + (size_t)srV * SS + scV;
  bf16x8 kr0, kr1, vr0, vr1;
#define LOADKV(t0) {                                             \
    const u16* gk_ = gK + (size_t)(t0) * EMB;                    \
    kr0 = *(const bf16x8*)gk_; kr1 = *(const bf16x8*)(gk_ + 8);  \
    const u16* gv_ = gV + (t0);                                  \
    vr0 = *(const bf16x8*)gv_; vr1 = *(const bf16x8*)(gv_ + 8); }
#define STOREKV(buf) {                                           \
    u16* ks_ = Ks0 + (buf) * (128 * 72) + srK * 72 + scK;        \
    *(bf16x8*)ks_ = kr0; *(bf16x8*)(ks_ + 8) = kr1;              \
    u16* vs_ = Vs0 + (buf) * (64 * 136) + srV * 136 + scV;       \
    *(bf16x8*)vs_ = vr0; *(bf16x8*)(vs_ + 8) = vr1; }

  // wave-uniform mask word base (scalar loads)
  const int thu = __builtin_amdgcn_readfirstlane(th);
  const int qgu = __builtin_amdgcn_readfirstlane(mtile * 2 + wq2);
  const uint64_t* mwb = MW + (((size_t)b * 64 + qgu) * 64) * 16 + thu * 16;
#define LOADMSK(m, it) {                                         \
    const uint64_t* mp_ = mwb + (size_t)(it) * 64;               \
    _Pragma("unroll")                                            \
    for (int r_ = 0; r_ < 16; ++r_) m[r_] = mp_[r_]; }

  float fNEG = -1e9f, fM0 = -M0;
  float lr = 0.f;
  f32x16 o0, o1;
#pragma unroll
  for (int r_ = 0; r_ < 16; ++r_) { o0[r_] = 0.f; o1[r_] = 0.f; }

  uint64_t mA[16], mB[16];
  LOADKV(0); LOADMSK(mA, 0);

#define BODY(it, buf, mc, mn) {                                                   \
    STOREKV(buf);                                                                 \
    __syncthreads();                                                              \
    if ((it) < 15) { LOADKV(((it) + 1) * 128); LOADMSK(mn, (it) + 1); }           \
    /* C-init: s[r] = maskbit ? -M0 : -1e9  (one cndmask/elem, SGPR-pair mask) */ \
    f32x16 s;                                                                     \
    _Pragma("unroll")                                                             \
    for (int r_ = 0; r_ < 16; ++r_) {                                             \
      float t_;                                                                   \
      asm("v_cndmask_b32 %0, %1, %2, %3"                                          \
          : "=v"(t_) : "v"(fNEG), "v"(fM0), "s"(mc[r_]));                         \
      s[r_] = t_;                                                                 \
    }                                                                             \
    /* S^T = K * Q^T over k=64 (4 chunks) */                                      \
    const u16* kb_ = Ks0 + (buf) * (128 * 72) + (th * 32 + c) * 72 + hi * 8;      \
    _Pragma("unroll")                                                             \
    for (int ks_ = 0; ks_ < 4; ++ks_) {                                           \
      bf16x8 kf_ = *(const bf16x8*)(kb_ + ks_ * 16);                              \
      s = __builtin_amdgcn_mfma_f32_32x32x16_bf16(kf_, aq[ks_], s, 0, 0, 0);      \
    }                                                                             \
    /* p = exp2(s); masked entries -> exp2(-1e9) = 0 */                           \
    _Pragma("unroll")                                                             \
    for (int r_ = 0; r_ < 16; ++r_) s[r_] = __builtin_amdgcn_exp2f(s[r_]);        \
    lr += ((s[0] + s[1]) + (s[2] + s[3])) + ((s[4] + s[5]) + (s[6] + s[7]))       \
        + ((s[8] + s[9]) + (s[10] + s[11])) + ((s[12] + s[13]) + (s[14] + s[15]));\
    /* in-register P -> PV B-frags: 8 pk2 + 4 permlane32_swap */                  \
    uint32_t x0 = pk2(s[0], s[1]),  x1 = pk2(s[2], s[3]);                         \
    uint32_t y0 = pk2(s[4], s[5]),  y1 = pk2(s[6], s[7]);                         \
    uint32_t z0 = pk2(s[8], s[9]),  z1 = pk2(s[10], s[11]);                       \
    uint32_t w0 = pk2(s[12], s[13]), w1 = pk2(s[14], s[15]);                      \
    asm("v_permlane32_swap_b32 %0, %1" : "+v"(x0), "+v"(y0));                     \
    asm("v_permlane32_swap_b32 %0, %1" : "+v"(x1), "+v"(y1));                     \
    asm("v_permlane32_swap_b32 %0, %1" : "+v"(z0), "+v"(w0));                     \
    asm("v_permlane32_swap_b32 %0, %1" : "+v"(z1), "+v"(w1));                     \
    bf16x8 pa0, pa1;                                                              \
    { union { uint32_t u[4]; bf16x8 v; } cv;                                      \
      cv.u[0] = x0; cv.u[1] = x1; cv.u[2] = y0; cv.u[3] = y1; pa0 = cv.v;         \
      cv.u[0] = z0; cv.u[1] = z1; cv.u[2] = w0; cv.u[3] = w1; pa1 = cv.v; }       \
    /* O^T += V^T * P^T : 2 d-groups x 2 t-chunks */                              \
    const u16* vb_ = Vs0 + (buf) * (64 * 136) + c * 136 + th * 32 + hi * 8;       \
    {                                                                             \
      bf16x8 vf_;                                                                 \
      vf_ = *(const bf16x8*)(vb_);                                                \
      o0 = __builtin_amdgcn_mfma_f32_32x32x16_bf16(vf_, pa0, o0, 0, 0, 0);        \
      vf_ = *(const bf16x8*)(vb_ + 16);                                           \
      o0 = __builtin_amdgcn_mfma_f32_32x32x16_bf16(vf_, pa1, o0, 0, 0, 0);        \
      vf_ = *(const bf16x8*)(vb_ + 32 * 136);                                     \
      o1 = __builtin_amdgcn_mfma_f32_32x32x16_bf16(vf_, pa0, o1, 0, 0, 0);        \
      vf_ = *(const bf16x8*)(vb_ + 32 * 136 + 16);                                \
      o1 = __builtin_amdgcn_mfma_f32_32x32x16_bf16(vf_, pa1, o1, 0, 0, 0);        \
    } }

  for (int i2 = 0; i2 < 8; ++i2) {
    BODY(i2 * 2,     0, mA, mB)
    BODY(i2 * 2 + 1, 1, mB, mA)
  }
#undef BODY
#undef LOADKV
#undef STOREKV
#undef LOADMSK

  // ---- cross-th reduction: partial O^T (f32) + partial l through LDS ----
  lr += __shfl_xor(lr, 32);                 // combine hi halves -> per-row partial for this th
  __syncthreads();                          // all waves done with Ks/Vs
  float* Of = (float*)sm;                   // [4 th][64 row][65]   (66560 B)
  float* Lf = (float*)sm + 4 * 64 * 65;     // [64 row][4 th]       (+1024 B) = 67584 <= 71680
  {
    int row = wq2 * 32 + c;
#pragma unroll
    for (int r_ = 0; r_ < 16; ++r_) {
      int d = (r_ & 3) + 8 * (r_ >> 2) + 4 * hi;
      Of[(th * 64 + row) * 65 + d]      = o0[r_];
      Of[(th * 64 + row) * 65 + 32 + d] = o1[r_];
    }
    if (hi == 0) Lf[row * 4 + th] = lr;
  }
  __syncthreads();
  {
    int qrow = tid >> 3, d0 = (tid & 7) * 8;
    float lt = Lf[qrow * 4 + 0] + Lf[qrow * 4 + 1] + Lf[qrow * 4 + 2] + Lf[qrow * 4 + 3];
    float inv = 1.f / fmaxf(lt, 1e-20f);
    float acc[8];
#pragma unroll
    for (int e = 0; e < 8; ++e) acc[e] = 0.f;
#pragma unroll
    for (int t_ = 0; t_ < 4; ++t_)
#pragma unroll
      for (int e = 0; e < 8; ++e) acc[e] += Of[(t_ * 64 + qrow) * 65 + d0 + e];
    uint32_t dw[4];
#pragma unroll
    for (int e = 0; e < 4; ++e) dw[e] = pk2(acc[2 * e] * inv, acc[2 * e + 1] * inv);
    *(uint4*)(AO + qkbase + (size_t)(m0 + qrow) * EMB + d0) = *(uint4*)dw;
  }
}

extern "C" void kernel_launch(void* const* d_in, const int* in_sizes, int n_in,
                              void* d_out, int out_size, void* d_ws, size_t ws_size,
                              hipStream_t stream) {
  const float* q  = (const float*)d_in[0];
  const float* k  = (const float*)d_in[1];
  const float* v  = (const float*)d_in[2];
  const int* mask = (const int*)d_in[3];
  const float* Wq = (const float*)d_in[4];
  const float* Wk = (const float*)d_in[5];
  const float* Wv = (const float*)d_in[6];
  const float* W  = (const float*)d_in[7];
  float* out = (float*)d_out;

  // d_out (12 MiB) as scratch for Kp + Vt, dead before gemm_out writes.
  u16* Kp = (u16*)d_out;                    // [b,s,h*64+d] bf16
  u16* Vt = (u16*)d_out + 3145728;          // [bh][d][t]   bf16

  // ws: 11.5 MiB
  u16* ws    = (u16*)d_ws;
  u16* Qp    = ws;                          // 3145728 u16; AO aliases
  u16* WqkvT = ws + 3145728;                // 1769472 u16
  u16* WT    = ws + 3145728 + 1769472;      // 589824 u16
  uint64_t* mb64 = (uint64_t*)(ws + 5505024); // 131072 u64 = 1 MiB
  u16* AO = Qp;

  pack_all<<<dim3(2624), 256, 0, stream>>>(Wq, Wk, Wv, W, mask, WqkvT, WT, mb64);
  gemm_qkv<<<dim3(1152), 256, 0, stream>>>(q, k, v, WqkvT, Qp, Kp, Vt);
  attn<<<dim3(768), 512, 0, stream>>>(Qp, Kp, Vt, mb64, AO);
  gemm_out<<<dim3(768), 256, 0, stream>>>(AO, WT, out);
}

// Round 11
// 203.323 us; speedup vs baseline: 1.1384x; 1.0296x over previous
//
#include <hip/hip_runtime.h>
#include <stdint.h>

typedef uint16_t u16;
typedef __attribute__((ext_vector_type(8))) short bf16x8;    // 8 bf16 (4 VGPRs)
typedef __attribute__((ext_vector_type(4))) float f32x4;     // MFMA C/D 16x16
typedef __attribute__((ext_vector_type(16))) float f32x16;   // MFMA C/D 32x32

#define EMB 768
#define NH 12
#define DK 64
#define BB 2
#define SS 2048
#define SCL 0.1803368801111244f   // 0.125 * log2(e)  (folded into Wq at pack time)
#define M0  24.0f                 // fixed softmax offset (log2 domain)

// gfx950 HW packed cvt: lo16 = bf16(a), hi16 = bf16(b), RNE
__device__ __forceinline__ uint32_t pk2(float a, float b) {
  uint32_t d;
  asm("v_cvt_pk_bf16_f32 %0, %1, %2" : "=v"(d) : "v"(a), "v"(b));
  return d;
}

__device__ __forceinline__ void gld16(const u16* g, u16* l) {
  __builtin_amdgcn_global_load_lds((const __attribute__((address_space(1))) void*)g,
                                   (__attribute__((address_space(3))) void*)l, 16, 0, 0);
}

// ---------------- pack_w: tiled-transpose weights only (576 blocks) ----------------
// 64x64 tile transpose through LDS (pad 65 -> <=2-way banks).
//   blocks 0..431: Wq/Wk/Wv  [h][e][d] -> wqkvT[z][n=h*64+d][e]   (z==0 scaled by SCL)
//   blocks 432..575: W       [e][n]    -> wT[n][e]
// The mask repack now rides inside the gemm_qkv launch (consumed only by the later
// attn kernel, so kernel-boundary ordering still guarantees completeness).
__global__ void pack_w(const float* __restrict__ wq, const float* __restrict__ wk,
                       const float* __restrict__ wv, const float* __restrict__ w,
                       u16* __restrict__ wqkvT, u16* __restrict__ wT) {
  __shared__ float L[65 * 64];              // 16.6 KB transpose tile
  const int bid = blockIdx.x, tid = threadIdx.x;
  const float* srcBase;
  int srcRowStride;
  u16* outBase;
  float scale = 1.0f;
  if (bid < 432) {
    int z = bid / 144, rest = bid - z * 144;
    int h = rest / 12, et = rest - h * 12;
    const float* src = z == 0 ? wq : (z == 1 ? wk : wv);
    srcBase = src + (size_t)h * (EMB * DK) + (size_t)(et * 64) * DK;   // + e*64 + d
    srcRowStride = DK;
    outBase = wqkvT + (size_t)z * (EMB * EMB) + (size_t)(h * 64) * EMB + et * 64; // + d*768 + e
    if (z == 0) scale = SCL;
  } else {
    int idx = bid - 432;
    int nt = idx / 12, et = idx - nt * 12;
    srcBase = w + (size_t)(et * 64) * EMB + nt * 64;                   // + e*768 + n'
    srcRowStride = EMB;
    outBase = wT + (size_t)(nt * 64) * EMB + et * 64;                  // + n'*768 + e
  }
  {   // coalesced read: thread = (row e = tid>>2, 16 cols at d0=(tid&3)*16); store L[e + 65*d]
    int e = tid >> 2, d0 = (tid & 3) * 16;
    const float* s_ = srcBase + (size_t)e * srcRowStride + d0;
    float4 v0 = *(const float4*)s_,       v1 = *(const float4*)(s_ + 4);
    float4 v2 = *(const float4*)(s_ + 8), v3 = *(const float4*)(s_ + 12);
    float tv[16] = { v0.x, v0.y, v0.z, v0.w, v1.x, v1.y, v1.z, v1.w,
                     v2.x, v2.y, v2.z, v2.w, v3.x, v3.y, v3.z, v3.w };
#pragma unroll
    for (int j = 0; j < 16; ++j) L[e + 65 * (d0 + j)] = tv[j];
  }
  __syncthreads();
  {   // coalesced write: thread = (out-row d = tid>>2, 16 cols at e0=(tid&3)*16)
    int d = tid >> 2, e0 = (tid & 3) * 16;
    uint32_t pk[8];
#pragma unroll
    for (int j = 0; j < 8; ++j)
      pk[j] = pk2(L[e0 + 2 * j + 65 * d] * scale, L[e0 + 2 * j + 1 + 65 * d] * scale);
    u16* o = outBase + (size_t)d * EMB + e0;
    *(uint4*)o = *(uint4*)pk;
    *(uint4*)(o + 8) = *(uint4*)(pk + 4);
  }
}

// ---------------- pipelined GEMM cores (C = A * Bt^T), BK=64, 8-slot XOR swizzle ----------------
// R9's proven discipline: __syncthreads, LDS dest LINEAR for gld16, pre-swizzled global
// source. 12 K-steps, 16 MFMA/step. slot ^= (row&7); read key qx8 = (ks*4+quad)^(c&7).
// Measured 0 bank conflicts.

// gemm_qkv core: A f32 global->regs (pk2-cvt, swizzled ds_write); Bt bf16 via gld16. 64x128 tile.
__device__ __forceinline__ void gemm_f32A_pipe(const float* __restrict__ A,
                                               const u16* __restrict__ Bt,
                                               int m0, int n0, u16* As, u16* Bs,
                                               f32x4 (&acc)[2][4]) {
  const int tid = threadIdx.x;
  const int lane = tid & 63, quad = lane >> 4, c = lane & 15;
  const int wr = (tid >> 6) >> 1, wc = (tid >> 6) & 1;
  const int arow = tid >> 2, a4 = tid & 3;          // A: 64 rows x 64 f32, 16 f32/thread
  const int s0 = (2 * a4) ^ (arow & 7);             // swizzled 16B-slot for lo 8 cols
  const int s1 = (2 * a4 + 1) ^ (arow & 7);         // swizzled 16B-slot for hi 8 cols
  float4 a0, a1, a2, a3;
#define LOAD_A(kk)                                                     \
  {                                                                    \
    const float* src = A + (size_t)(m0 + arow) * EMB + (kk) + a4 * 16; \
    a0 = *(const float4*)src;       a1 = *(const float4*)(src + 4);    \
    a2 = *(const float4*)(src + 8); a3 = *(const float4*)(src + 12);   \
  }
#define ISSUE_B(kk, buf)                                               \
  _Pragma("unroll")                                                    \
  for (int r = 0; r < 4; ++r) {                                        \
    int bo = r * 4096 + tid * 16;   /* byte off in 128x64u16 (128B/row) */ \
    int brow = bo >> 7, bslot = (bo >> 4) & 7;                         \
    gld16(Bt + (size_t)(n0 + brow) * EMB + (kk) + (bslot ^ (brow & 7)) * 8, \
          Bs + (buf) * 8192 + (bo >> 1));        /* LDS dest linear */ \
  }
  LOAD_A(0); ISSUE_B(0, 0);
  for (int kk = 0; kk < EMB; kk += 64) {
    const int buf = (kk >> 6) & 1;
    {                                             // write A(kk) regs -> As[buf] (swizzled slots)
      uint4 p0 = { pk2(a0.x, a0.y), pk2(a0.z, a0.w), pk2(a1.x, a1.y), pk2(a1.z, a1.w) };
      uint4 p1 = { pk2(a2.x, a2.y), pk2(a2.z, a2.w), pk2(a3.x, a3.y), pk2(a3.z, a3.w) };
      *(uint4*)(As + buf * 4096 + arow * 64 + s0 * 8) = p0;
      *(uint4*)(As + buf * 4096 + arow * 64 + s1 * 8) = p1;
    }
    __syncthreads();                              // drains B(kk) DMA + A writes
    if (kk + 64 < EMB) { LOAD_A(kk + 64); ISSUE_B(kk + 64, buf ^ 1); }
    const u16* Ab = As + buf * 4096;
    const u16* Bb = Bs + buf * 8192;
#pragma unroll
    for (int ks = 0; ks < 2; ++ks) {
      const int qx8 = (ks * 4 + quad) ^ (c & 7);
      bf16x8 af[2], bfr[4];
#pragma unroll
      for (int i = 0; i < 2; ++i)
        af[i] = *(const bf16x8*)(Ab + (wr * 32 + i * 16 + c) * 64 + qx8 * 8);
#pragma unroll
      for (int j = 0; j < 4; ++j)
        bfr[j] = *(const bf16x8*)(Bb + (wc * 64 + j * 16 + c) * 64 + qx8 * 8);
#pragma unroll
      for (int i = 0; i < 2; ++i)
#pragma unroll
        for (int j = 0; j < 4; ++j)
          acc[i][j] = __builtin_amdgcn_mfma_f32_16x16x32_bf16(af[i], bfr[j], acc[i][j], 0, 0, 0);
    }
  }
#undef LOAD_A
#undef ISSUE_B
}

// gemm_out core: both operands bf16 via gld16, pre-swizzled sources. 64x64 tile, acc[2][2].
__device__ __forceinline__ void gemm_bf16A_pipe(const u16* __restrict__ A,
                                                const u16* __restrict__ Bt,
                                                int m0, int n0, u16* As, u16* Bs,
                                                f32x4 (&acc)[2][2]) {
  const int tid = threadIdx.x;
  const int lane = tid & 63, quad = lane >> 4, c = lane & 15;
  const int wr = (tid >> 6) >> 1, wc = (tid >> 6) & 1;
#define ISSUE_AB(kk, buf)                                              \
  {                                                                    \
    _Pragma("unroll")                                                  \
    for (int r = 0; r < 2; ++r) {   /* A: 64x64u16 = 8KB/buf */        \
      int ao = r * 4096 + tid * 16;                                    \
      int arw = ao >> 7, asl = (ao >> 4) & 7;                          \
      gld16(A + (size_t)(m0 + arw) * EMB + (kk) + (asl ^ (arw & 7)) * 8, \
            As + (buf) * 4096 + (ao >> 1));                            \
    }                                                                  \
    _Pragma("unroll")                                                  \
    for (int r = 0; r < 2; ++r) {   /* B: 64x64u16 = 8KB/buf */        \
      int bo = r * 4096 + tid * 16;                                    \
      int brw = bo >> 7, bsl = (bo >> 4) & 7;                          \
      gld16(Bt + (size_t)(n0 + brw) * EMB + (kk) + (bsl ^ (brw & 7)) * 8, \
            Bs + (buf) * 4096 + (bo >> 1));                            \
    }                                                                  \
  }
  ISSUE_AB(0, 0);
  for (int kk = 0; kk < EMB; kk += 64) {
    const int buf = (kk >> 6) & 1;
    __syncthreads();                              // drains DMA(kk)
    if (kk + 64 < EMB) { ISSUE_AB(kk + 64, buf ^ 1); }
    const u16* Ab = As + buf * 4096;
    const u16* Bb = Bs + buf * 4096;
#pragma unroll
    for (int ks = 0; ks < 2; ++ks) {
      const int qx8 = (ks * 4 + quad) ^ (c & 7);
      bf16x8 af[2], bfr[2];
#pragma unroll
      for (int i = 0; i < 2; ++i)
        af[i] = *(const bf16x8*)(Ab + (wr * 32 + i * 16 + c) * 64 + qx8 * 8);
#pragma unroll
      for (int j = 0; j < 2; ++j)
        bfr[j] = *(const bf16x8*)(Bb + (wc * 32 + j * 16 + c) * 64 + qx8 * 8);
#pragma unroll
      for (int i = 0; i < 2; ++i)
#pragma unroll
        for (int j = 0; j < 2; ++j)
          acc[i][j] = __builtin_amdgcn_mfma_f32_16x16x32_bf16(af[i], bfr[j], acc[i][j], 0, 0, 0);
    }
  }
#undef ISSUE_AB
}

// blocks [0,1152): z=0: Q -> Qp; z=1: K -> Kp; z=2: V -> Vt[bh][d][t].
//   XCD-panel swizzle: each XCD owns 24 A-panels x 6 n-tiles.
// blocks [1152,3200): mask repack (consumed only by the LATER attn kernel, so
//   kernel-boundary ordering guarantees completeness; rides in gemm_qkv's idle
//   HBM bandwidth / latency bubbles instead of a serial pack pass).
//   u64 word W[b][qg][tg][r], bit l = mask[b][qg*32+(l&31)][tg*32+(r&3)+8*(r>>2)+4*(l>>5)] != 0
__launch_bounds__(256, 3)
__global__ void gemm_qkv(const float* __restrict__ q, const float* __restrict__ k,
                         const float* __restrict__ v, const u16* __restrict__ wt3,
                         const int* __restrict__ mask,
                         u16* __restrict__ Qp, u16* __restrict__ Kp, u16* __restrict__ Vt,
                         uint64_t* __restrict__ bits) {
  __shared__ __align__(16) u16 As[2 * 64 * 64];    // 16 KB dbuf
  __shared__ __align__(16) u16 Bs[2 * 128 * 64];   // 32 KB dbuf
  const int id = blockIdx.x;
  if (id >= 1152) {                          // ---- mask repack rider ----
    uint32_t widx = (uint32_t)(id - 1152) * 256 + threadIdx.x;  // [0, 524288)
    uint32_t wv64 = widx >> 6;
    uint32_t lane = widx & 63;
    uint32_t b  = wv64 >> 12;
    uint32_t qg = (wv64 >> 6) & 63;
    uint32_t tg = wv64 & 63;
    uint32_t c = lane & 31, hi = lane >> 5;
    const int* mp = mask + (((size_t)b * 2048 + qg * 32 + c) * 2048 + tg * 32 + hi * 4);
    int4 q0 = *(const int4*)mp;
    int4 q1 = *(const int4*)(mp + 8);
    int4 q2 = *(const int4*)(mp + 16);
    int4 q3 = *(const int4*)(mp + 24);
    uint64_t* wout = bits + (size_t)wv64 * 16;
    unsigned long long ball;
#define BAL(u, arr)                                                   \
    ball = __ballot(arr.x != 0); if (lane == 0) wout[u * 4 + 0] = ball; \
    ball = __ballot(arr.y != 0); if (lane == 0) wout[u * 4 + 1] = ball; \
    ball = __ballot(arr.z != 0); if (lane == 0) wout[u * 4 + 2] = ball; \
    ball = __ballot(arr.w != 0); if (lane == 0) wout[u * 4 + 3] = ball;
    BAL(0, q0) BAL(1, q1) BAL(2, q2) BAL(3, q3)
#undef BAL
    return;
  }
  const int xcd = id & 7, s = id >> 3;       // s: 0..143
  const int panel = xcd * 24 + s / 6;        // 0..191 (z*64 + mtile)
  const int ntile = s - (s / 6) * 6;
  const int z = panel >> 6, mt = panel & 63;
  const int m0 = mt * 64, n0 = ntile * 128;
  const float* A = z == 0 ? q : (z == 1 ? k : v);
  const u16* Bt = wt3 + (size_t)z * EMB * EMB;
  f32x4 acc[2][4];
  const f32x4 fz = {0.f, 0.f, 0.f, 0.f};
#pragma unroll
  for (int i = 0; i < 2; ++i)
#pragma unroll
    for (int j = 0; j < 4; ++j) acc[i][j] = fz;
  gemm_f32A_pipe(A, Bt, m0, n0, As, Bs, acc);
  const int tid = threadIdx.x, lane = tid & 63, quad = lane >> 4, c = lane & 15;
  const int wr = (tid >> 6) >> 1, wc = (tid >> 6) & 1;
  if (z < 2) {
    u16* C = z == 0 ? Qp : Kp;
#pragma unroll
    for (int i = 0; i < 2; ++i)
#pragma unroll
      for (int j = 0; j < 4; ++j) {
        int row = m0 + wr * 32 + i * 16 + quad * 4;
        int col = n0 + wc * 64 + j * 16 + c;
#pragma unroll
        for (int r = 0; r < 4; r += 2) {
          uint32_t d = pk2(acc[i][j][r], acc[i][j][r + 1]);
          C[(size_t)(row + r) * EMB + col] = (u16)d;
          C[(size_t)(row + r + 1) * EMB + col] = (u16)(d >> 16);
        }
      }
  } else {
#pragma unroll
    for (int i = 0; i < 2; ++i)
#pragma unroll
      for (int j = 0; j < 4; ++j) {
        int row = m0 + wr * 32 + i * 16 + quad * 4;   // + r -> consecutive s
        int col = n0 + wc * 64 + j * 16 + c;          // n = h*64+d
        int b = row >> 11, ss = row & 2047;
        int h = col >> 6, d = col & 63;
        uint2 pk = { pk2(acc[i][j][0], acc[i][j][1]), pk2(acc[i][j][2], acc[i][j][3]) };
        *(uint2*)(Vt + ((size_t)(b * NH + h) * DK + d) * SS + ss) = pk;
      }
  }
}

// 1-D grid 768 (64x64 tiles -> 3 blocks/CU exact), XCD-panel swizzle: 8 panels x 12 n-tiles/XCD.
__launch_bounds__(256, 4)
__global__ void gemm_out(const u16* __restrict__ A, const u16* __restrict__ Bt,
                         float* __restrict__ C) {
  __shared__ __align__(16) u16 As[2 * 64 * 64];    // 16 KB dbuf
  __shared__ __align__(16) u16 Bs[2 * 64 * 64];    // 16 KB dbuf
  const int id = blockIdx.x;                 // 0..767
  const int xcd = id & 7, s = id >> 3;       // s: 0..95
  const int panel = xcd * 8 + s / 12;        // 0..63
  const int ntile = s - (s / 12) * 12;       // 0..11
  const int m0 = panel * 64, n0 = ntile * 64;
  f32x4 acc[2][2];
  const f32x4 fz = {0.f, 0.f, 0.f, 0.f};
#pragma unroll
  for (int i = 0; i < 2; ++i)
#pragma unroll
    for (int j = 0; j < 2; ++j) acc[i][j] = fz;
  gemm_bf16A_pipe(A, Bt, m0, n0, As, Bs, acc);
  const int tid = threadIdx.x, lane = tid & 63, quad = lane >> 4, c = lane & 15;
  const int wr = (tid >> 6) >> 1, wc = (tid >> 6) & 1;
#pragma unroll
  for (int i = 0; i < 2; ++i)
#pragma unroll
    for (int j = 0; j < 2; ++j)
#pragma unroll
      for (int r = 0; r < 4; ++r) {
        int row = m0 + wr * 32 + i * 16 + quad * 4 + r;
        int col = n0 + wc * 32 + j * 16 + c;
        C[(size_t)row * EMB + col] = acc[i][j][r];   // raw fp32
      }
}

// ---------------- flash attention v6: 32x32 swapped MFMA, in-register softmax ----------------
// Grid 768 (1D, XCD-swizzled): block = (bh, 64-q tile). 8 waves = (wq2: q 32-group) x (th: t slice).
__launch_bounds__(512, 4)
__global__ void attn(const u16* __restrict__ Qp, const u16* __restrict__ Kp,
                     const u16* __restrict__ Vt, const uint64_t* __restrict__ MW,
                     u16* __restrict__ AO) {
  // Ks: [2][128 t][72]  (18432 u16)   Vs: [2][64 d][136] (17408 u16)  = 71680 B
  __shared__ __align__(16) u16 sm[2 * 128 * 72 + 2 * 64 * 136];
  u16* Ks0 = sm;
  u16* Vs0 = sm + 2 * 128 * 72;

  const int tid = threadIdx.x, lane = tid & 63;
  const int c = lane & 31, hi = lane >> 5;
  const int w = tid >> 6;
  const int wq2 = w >> 2, th = w & 3;

  // XCD swizzle: blockIdx.x % 8 = XCD -> all 32 q-tiles of a head stay on one XCD (K/V L2-resident)
  const int wid = blockIdx.x;
  const int xcd = wid & 7, slot = wid >> 3;        // slot 0..95
  const int bh = xcd + 8 * (slot >> 5);            // 0..23
  const int mtile = slot & 31;
  const int b = bh / NH, h = bh - b * NH;
  const int m0 = mtile * 64;

  const size_t qkbase = (size_t)b * SS * EMB + (size_t)h * DK;
  const size_t vtbase = (size_t)bh * DK * SS;

  // Q fragments (B-operand): lane holds Q[q = m0+wq2*32+c][k = ks*16 + hi*8 + e]
  bf16x8 aq[4];
  {
    const u16* qr = Qp + qkbase + (size_t)(m0 + wq2 * 32 + c) * EMB + hi * 8;
    aq[0] = *(const bf16x8*)(qr);
    aq[1] = *(const bf16x8*)(qr + 16);
    aq[2] = *(const bf16x8*)(qr + 32);
    aq[3] = *(const bf16x8*)(qr + 48);
  }

  // staging: K tile 128x64, V^T tile 64x128 -> 32B per thread each array
  const int srK = tid >> 2, scK = (tid & 3) * 16;
  const int srV = tid >> 3, scV = (tid & 7) * 16;
  const u16* gK = Kp + qkbase + (size_t)srK * EMB + scK;
  const u16* gV = Vt + vtbase + (size_t)srV * SS + scV;
  bf16x8 kr0, kr1, vr0, vr1;
#define LOADKV(t0) {                                             \
    const u16* gk_ = gK + (size_t)(t0) * EMB;                    \
    kr0 = *(const bf16x8*)gk_; kr1 = *(const bf16x8*)(gk_ + 8);  \
    const u16* gv_ = gV + (t0);                                  \
    vr0 = *(const bf16x8*)gv_; vr1 = *(const bf16x8*)(gv_ + 8); }
#define STOREKV(buf) {                                           \
    u16* ks_ = Ks0 + (buf) * (128 * 72) + srK * 72 + scK;        \
    *(bf16x8*)ks_ = kr0; *(bf16x8*)(ks_ + 8) = kr1;              \
    u16* vs_ = Vs0 + (buf) * (64 * 136) + srV * 136 + scV;       \
    *(bf16x8*)vs_ = vr0; *(bf16x8*)(vs_ + 8) = vr1; }

  // wave-uniform mask word base (scalar loads)
  const int thu = __builtin_amdgcn_readfirstlane(th);
  const int qgu = __builtin_amdgcn_readfirstlane(mtile * 2 + wq2);
  const uint64_t* mwb = MW + (((size_t)b * 64 + qgu) * 64) * 16 + thu * 16;
#define LOADMSK(m, it) {                                         \
    const uint64_t* mp_ = mwb + (size_t)(it) * 64;               \
    _Pragma("unroll")                                            \
    for (int r_ = 0; r_ < 16; ++r_) m[r_] = mp_[r_]; }

  float fNEG = -1e9f, fM0 = -M0;
  float lr = 0.f;
  f32x16 o0, o1;
#pragma unroll
  for (int r_ = 0; r_ < 16; ++r_) { o0[r_] = 0.f; o1[r_] = 0.f; }

  uint64_t mA[16], mB[16];
  LOADKV(0); LOADMSK(mA, 0);

#define BODY(it, buf, mc, mn) {                                                   \
    STOREKV(buf);                                                                 \
    __syncthreads();                                                              \
    if ((it) < 15) { LOADKV(((it) + 1) * 128); LOADMSK(mn, (it) + 1); }           \
    /* C-init: s[r] = maskbit ? -M0 : -1e9  (one cndmask/elem, SGPR-pair mask) */ \
    f32x16 s;                                                                     \
    _Pragma("unroll")                                                             \
    for (int r_ = 0; r_ < 16; ++r_) {                                             \
      float t_;                                                                   \
      asm("v_cndmask_b32 %0, %1, %2, %3"                                          \
          : "=v"(t_) : "v"(fNEG), "v"(fM0), "s"(mc[r_]));                         \
      s[r_] = t_;                                                                 \
    }                                                                             \
    /* S^T = K * Q^T over k=64 (4 chunks) */                                      \
    const u16* kb_ = Ks0 + (buf) * (128 * 72) + (th * 32 + c) * 72 + hi * 8;      \
    _Pragma("unroll")                                                             \
    for (int ks_ = 0; ks_ < 4; ++ks_) {                                           \
      bf16x8 kf_ = *(const bf16x8*)(kb_ + ks_ * 16);                              \
      s = __builtin_amdgcn_mfma_f32_32x32x16_bf16(kf_, aq[ks_], s, 0, 0, 0);      \
    }                                                                             \
    /* p = exp2(s); masked entries -> exp2(-1e9) = 0 */                           \
    _Pragma("unroll")                                                             \
    for (int r_ = 0; r_ < 16; ++r_) s[r_] = __builtin_amdgcn_exp2f(s[r_]);        \
    lr += ((s[0] + s[1]) + (s[2] + s[3])) + ((s[4] + s[5]) + (s[6] + s[7]))       \
        + ((s[8] + s[9]) + (s[10] + s[11])) + ((s[12] + s[13]) + (s[14] + s[15]));\
    /* in-register P -> PV B-frags: 8 pk2 + 4 permlane32_swap */                  \
    uint32_t x0 = pk2(s[0], s[1]),  x1 = pk2(s[2], s[3]);                         \
    uint32_t y0 = pk2(s[4], s[5]),  y1 = pk2(s[6], s[7]);                         \
    uint32_t z0 = pk2(s[8], s[9]),  z1 = pk2(s[10], s[11]);                       \
    uint32_t w0 = pk2(s[12], s[13]), w1 = pk2(s[14], s[15]);                      \
    asm("v_permlane32_swap_b32 %0, %1" : "+v"(x0), "+v"(y0));                     \
    asm("v_permlane32_swap_b32 %0, %1" : "+v"(x1), "+v"(y1));                     \
    asm("v_permlane32_swap_b32 %0, %1" : "+v"(z0), "+v"(w0));                     \
    asm("v_permlane32_swap_b32 %0, %1" : "+v"(z1), "+v"(w1));                     \
    bf16x8 pa0, pa1;                                                              \
    { union { uint32_t u[4]; bf16x8 v; } cv;                                      \
      cv.u[0] = x0; cv.u[1] = x1; cv.u[2] = y0; cv.u[3] = y1; pa0 = cv.v;         \
      cv.u[0] = z0; cv.u[1] = z1; cv.u[2] = w0; cv.u[3] = w1; pa1 = cv.v; }       \
    /* O^T += V^T * P^T : 2 d-groups x 2 t-chunks */                              \
    const u16* vb_ = Vs0 + (buf) * (64 * 136) + c * 136 + th * 32 + hi * 8;       \
    {                                                                             \
      bf16x8 vf_;                                                                 \
      vf_ = *(const bf16x8*)(vb_);                                                \
      o0 = __builtin_amdgcn_mfma_f32_32x32x16_bf16(vf_, pa0, o0, 0, 0, 0);        \
      vf_ = *(const bf16x8*)(vb_ + 16);                                           \
      o0 = __builtin_amdgcn_mfma_f32_32x32x16_bf16(vf_, pa1, o0, 0, 0, 0);        \
      vf_ = *(const bf16x8*)(vb_ + 32 * 136);                                     \
      o1 = __builtin_amdgcn_mfma_f32_32x32x16_bf16(vf_, pa0, o1, 0, 0, 0);        \
      vf_ = *(const bf16x8*)(vb_ + 32 * 136 + 16);                                \
      o1 = __builtin_amdgcn_mfma_f32_32x32x16_bf16(vf_, pa1, o1, 0, 0, 0);        \
    } }

  for (int i2 = 0; i2 < 8; ++i2) {
    BODY(i2 * 2,     0, mA, mB)
    BODY(i2 * 2 + 1, 1, mB, mA)
  }
#undef BODY
#undef LOADKV
#undef STOREKV
#undef LOADMSK

  // ---- cross-th reduction: partial O^T (f32) + partial l through LDS ----
  lr += __shfl_xor(lr, 32);                 // combine hi halves -> per-row partial for this th
  __syncthreads();                          // all waves done with Ks/Vs
  float* Of = (float*)sm;                   // [4 th][64 row][65]   (66560 B)
  float* Lf = (float*)sm + 4 * 64 * 65;     // [64 row][4 th]       (+1024 B) = 67584 <= 71680
  {
    int row = wq2 * 32 + c;
#pragma unroll
    for (int r_ = 0; r_ < 16; ++r_) {
      int d = (r_ & 3) + 8 * (r_ >> 2) + 4 * hi;
      Of[(th * 64 + row) * 65 + d]      = o0[r_];
      Of[(th * 64 + row) * 65 + 32 + d] = o1[r_];
    }
    if (hi == 0) Lf[row * 4 + th] = lr;
  }
  __syncthreads();
  {
    int qrow = tid >> 3, d0 = (tid & 7) * 8;
    float lt = Lf[qrow * 4 + 0] + Lf[qrow * 4 + 1] + Lf[qrow * 4 + 2] + Lf[qrow * 4 + 3];
    float inv = 1.f / fmaxf(lt, 1e-20f);
    float acc[8];
#pragma unroll
    for (int e = 0; e < 8; ++e) acc[e] = 0.f;
#pragma unroll
    for (int t_ = 0; t_ < 4; ++t_)
#pragma unroll
      for (int e = 0; e < 8; ++e) acc[e] += Of[(t_ * 64 + qrow) * 65 + d0 + e];
    uint32_t dw[4];
#pragma unroll
    for (int e = 0; e < 4; ++e) dw[e] = pk2(acc[2 * e] * inv, acc[2 * e + 1] * inv);
    *(uint4*)(AO + qkbase + (size_t)(m0 + qrow) * EMB + d0) = *(uint4*)dw;
  }
}

extern "C" void kernel_launch(void* const* d_in, const int* in_sizes, int n_in,
                              void* d_out, int out_size, void* d_ws, size_t ws_size,
                              hipStream_t stream) {
  const float* q  = (const float*)d_in[0];
  const float* k  = (const float*)d_in[1];
  const float* v  = (const float*)d_in[2];
  const int* mask = (const int*)d_in[3];
  const float* Wq = (const float*)d_in[4];
  const float* Wk = (const float*)d_in[5];
  const float* Wv = (const float*)d_in[6];
  const float* W  = (const float*)d_in[7];
  float* out = (float*)d_out;

  // d_out (12 MiB) as scratch for Kp + Vt, dead before gemm_out writes.
  u16* Kp = (u16*)d_out;                    // [b,s,h*64+d] bf16
  u16* Vt = (u16*)d_out + 3145728;          // [bh][d][t]   bf16

  // ws: 11.5 MiB
  u16* ws    = (u16*)d_ws;
  u16* Qp    = ws;                          // 3145728 u16; AO aliases
  u16* WqkvT = ws + 3145728;                // 1769472 u16
  u16* WT    = ws + 3145728 + 1769472;      // 589824 u16
  uint64_t* mb64 = (uint64_t*)(ws + 5505024); // 131072 u64 = 1 MiB
  u16* AO = Qp;

  pack_w<<<dim3(576), 256, 0, stream>>>(Wq, Wk, Wv, W, WqkvT, WT);
  gemm_qkv<<<dim3(3200), 256, 0, stream>>>(q, k, v, WqkvT, mask, Qp, Kp, Vt, mb64);
  attn<<<dim3(768), 512, 0, stream>>>(Qp, Kp, Vt, mb64, AO);
  gemm_out<<<dim3(768), 256, 0, stream>>>(AO, WT, out);
}